// Round 5
// baseline (1556.814 us; speedup 1.0000x reference)
//
#include <hip/hip_runtime.h>
#include <stdint.h>
#include <stddef.h>

#define Bn    16
#define Nn    10000
#define En    320000
#define CIN   32
#define COUTn 64
#define CCn   96
#define WROWU 768           // uints per full node row (16 batches * 96ch / 2)
#define RHU   512           // uints per rh-only node row (16 * 64 / 2)
#define MROWS 160000        // Nn * Bn

typedef __attribute__((ext_vector_type(8))) short short8;   // 8 bf16 = 4 VGPRs
typedef __attribute__((ext_vector_type(4))) float f32x4;
typedef __attribute__((ext_vector_type(2))) unsigned int uint2v;

// ---------------- bf16 helpers ----------------
__device__ __forceinline__ float bflo(unsigned int p) { return __uint_as_float(p << 16); }
__device__ __forceinline__ float bfhi(unsigned int p) { return __uint_as_float(p & 0xffff0000u); }
__device__ __forceinline__ float bf2f(unsigned short u) { return __uint_as_float(((unsigned int)u) << 16); }
__device__ __forceinline__ unsigned int f2bfbits(float f) {
  unsigned int x = __float_as_uint(f);
  return (x + 0x7fffu + ((x >> 16) & 1u)) >> 16;
}
__device__ __forceinline__ unsigned int pack2(float lo, float hi) {
  return f2bfbits(lo) | (f2bfbits(hi) << 16);
}

// ---------------- edge_index dtype detection ----------------
__global__ void detect_idx(const int* __restrict__ idx, int* __restrict__ flag) {
  if (threadIdx.x == 0 && blockIdx.x == 0) {
    int is64 = 1;
    for (int i = 1; i < 128; i += 2) {
      if (idx[i] != 0) { is64 = 0; break; }
    }
    flag[0] = is64;
  }
}

__device__ __forceinline__ int gidx(const int* __restrict__ p, int i, int is64) {
  return is64 ? p[2 * (long long)i] : p[i];
}

// ---------------- degree + CSR row counts ----------------
__global__ void deg_cnt_kernel(const int* __restrict__ idx, const float* __restrict__ w,
                               float* __restrict__ deg_f, float* __restrict__ deg_b,
                               int* __restrict__ cnt_f, int* __restrict__ cnt_b,
                               const int* __restrict__ flag) {
  int e = blockIdx.x * 256 + threadIdx.x;
  int is64 = flag[0];
  if (e < En) {
    int s = gidx(idx, e, is64);
    int d = gidx(idx, En + e, is64);
    float we = w[e];
    atomicAdd(&deg_f[s], we);
    atomicAdd(&deg_b[d], we);
    atomicAdd(&cnt_f[d], 1);
    atomicAdd(&cnt_b[s], 1);
  }
}

// ---------------- exclusive scan ----------------
__global__ void exscan_two(const int* __restrict__ cnt_f, const int* __restrict__ cnt_b,
                           int* __restrict__ rp_f, int* __restrict__ rp_b,
                           int* __restrict__ cur_f, int* __restrict__ cur_b, int n) {
  const int* cnt = (blockIdx.x == 0) ? cnt_f : cnt_b;
  int* rp  = (blockIdx.x == 0) ? rp_f  : rp_b;
  int* cur = (blockIdx.x == 0) ? cur_f : cur_b;
  __shared__ int sh[256];
  int t = threadIdx.x;
  int running = 0;
  for (int base = 0; base < n; base += 256) {
    int v = (base + t < n) ? cnt[base + t] : 0;
    sh[t] = v;
    __syncthreads();
    for (int off = 1; off < 256; off <<= 1) {
      int x = (t >= off) ? sh[t - off] : 0;
      __syncthreads();
      sh[t] += x;
      __syncthreads();
    }
    int excl = sh[t] - v;
    if (base + t < n) { rp[base + t] = running + excl; cur[base + t] = running + excl; }
    int total = sh[255];
    __syncthreads();
    running += total;
  }
  if (t == 0) rp[n] = running;
}

// ---------------- CSR fill: packed (col, w) uint2 ----------------
__global__ void fill_csr(const int* __restrict__ idx, const float* __restrict__ w,
                         const float* __restrict__ deg_f, const float* __restrict__ deg_b,
                         int* __restrict__ cur_f, int* __restrict__ cur_b,
                         uint2v* __restrict__ cwf, uint2v* __restrict__ cwb,
                         const int* __restrict__ flag) {
  int e = blockIdx.x * 256 + threadIdx.x;
  int is64 = flag[0];
  if (e < En) {
    int s = gidx(idx, e, is64);
    int d = gidx(idx, En + e, is64);
    float we = w[e];
    int pf = atomicAdd(&cur_f[d], 1);
    uint2v ef; ef.x = (unsigned int)s; ef.y = __float_as_uint(we / deg_f[s]);
    cwf[pf] = ef;
    int pb = atomicAdd(&cur_b[s], 1);
    uint2v eb; eb.x = (unsigned int)d; eb.y = __float_as_uint(we / deg_b[d]);
    cwb[pb] = eb;
  }
}

// ---------------- weight prep: transposed bf16, W0 folded (W0-W3-W4) ----------------
__global__ void build_wt(const float* __restrict__ ru_p, const float* __restrict__ c_p,
                         unsigned short* __restrict__ Wt1, unsigned short* __restrict__ Wt2) {
  int i = blockIdx.x * 256 + threadIdx.x;
  if (i < 128 * 480) {
    int n = i / 480, k = i % 480;
    int t = k / 96, kk = k % 96;
    float v;
    if (t == 0) v = ru_p[(kk * 5 + 0) * 128 + n] - ru_p[(kk * 5 + 3) * 128 + n] - ru_p[(kk * 5 + 4) * 128 + n];
    else        v = ru_p[(kk * 5 + t) * 128 + n];
    Wt1[i] = (unsigned short)f2bfbits(v);
  }
  if (i < 64 * 480) {
    int n = i / 480, k = i % 480;
    int t = k / 96, kk = k % 96;
    float v;
    if (t == 0) v = c_p[(kk * 5 + 0) * 64 + n] - c_p[(kk * 5 + 3) * 64 + n] - c_p[(kk * 5 + 4) * 64 + n];
    else        v = c_p[(kk * 5 + t) * 64 + n];
    Wt2[i] = (unsigned short)f2bfbits(v);
  }
}

// ---------------- X0 builder ----------------
__global__ void build_x0_ru(const float* __restrict__ x, const float* __restrict__ h,
                            unsigned int* __restrict__ X0) {
  long long p = (long long)blockIdx.x * 256 + threadIdx.x;
  int node = (int)(p / WROWU);
  int rem = (int)(p % WROWU);
  int b = rem / 48;
  int ci = (rem % 48) * 2;
  float lo, hi;
  if (ci < CIN) {
    const float* s = x + ((size_t)b * Nn + node) * CIN + ci;
    lo = s[0]; hi = s[1];
  } else {
    const float* s = h + ((size_t)b * Nn + node) * COUTn + (ci - CIN);
    lo = s[0]; hi = s[1];
  }
  X0[p] = pack2(lo, hi);
}

// ============ XCD-sliced propagation (R1 layout, deeper MLP) ============
// Node rows of RU2 uint2 split into 8 channel slices; slice = blockIdx & 7
// -> each XCD gathers only its own 3.84 MB (conv1) / 2.56 MB (conv2) slice,
// L2-resident (verified: FETCH 627->175 MB).  One row per wave.
// conv1: lanes 0..47 each own one uint2 of the 48-uint2 slice.
// conv2: 32-lane groups; lanes 0-31 edge i, 32-63 edge i+1 (full lane util).
// Main loops keep 8 gathers in flight (latency-bound regime, see R4 PM).
// Edge loads / stores nontemporal; gathers cached (they are the reuse).

// ---- conv1 row: 48 active lanes, unroll 8 ----
__device__ __forceinline__ void p1_row(const uint2v* __restrict__ in,
                                       uint2v* __restrict__ out,
                                       const int* __restrict__ rp,
                                       const uint2v* __restrict__ cw,
                                       int row, int uoff, bool act, float alpha) {
  int jb = rp[row], je = rp[row + 1];
  int len = je - jb;
  const uint2v* __restrict__ base = in + uoff;
  float a0 = 0.f, a1 = 0.f, a2 = 0.f, a3 = 0.f;
  int lenM = len & ~7;
  int i = 0;
  for (; i < lenM; i += 8) {
    uint2v e[8], q[8];
    #pragma unroll
    for (int k = 0; k < 8; ++k) e[k] = __builtin_nontemporal_load(&cw[jb + i + k]);
    #pragma unroll
    for (int k = 0; k < 8; ++k) q[k] = base[(size_t)e[k].x * 384];
    #pragma unroll
    for (int k = 0; k < 8; ++k) {
      float w = __uint_as_float(e[k].y);
      a0 += w * bflo(q[k].x); a1 += w * bfhi(q[k].x);
      a2 += w * bflo(q[k].y); a3 += w * bfhi(q[k].y);
    }
  }
  if (i < len) {
    uint2v e[8], q[8];
    float wv[8];
    #pragma unroll
    for (int k = 0; k < 8; ++k) {
      bool v = (i + k) < len;
      e[k] = __builtin_nontemporal_load(&cw[jb + (v ? i + k : 0)]);
      wv[k] = v ? __uint_as_float(e[k].y) : 0.f;
    }
    #pragma unroll
    for (int k = 0; k < 8; ++k) q[k] = base[(size_t)e[k].x * 384];
    #pragma unroll
    for (int k = 0; k < 8; ++k) {
      a0 += wv[k] * bflo(q[k].x); a1 += wv[k] * bfhi(q[k].x);
      a2 += wv[k] * bflo(q[k].y); a3 += wv[k] * bfhi(q[k].y);
    }
  }
  if (act) {
    uint2v o; o.x = pack2(alpha * a0, alpha * a1); o.y = pack2(alpha * a2, alpha * a3);
    __builtin_nontemporal_store(o, &out[(size_t)row * 384 + uoff]);
  }
}

__launch_bounds__(256)
__global__ void prop1_dual(const uint2v* __restrict__ in,
                           uint2v* __restrict__ outF, uint2v* __restrict__ outB,
                           const int* __restrict__ rp_f, const uint2v* __restrict__ cwf,
                           const int* __restrict__ rp_b, const uint2v* __restrict__ cwb) {
  int lane = threadIdx.x & 63;
  int wave = threadIdx.x >> 6;
  int slice = blockIdx.x & 7;
  int row = (blockIdx.x >> 3) * 4 + wave;
  int l = lane < 48 ? lane : 47;          // clamp pad lanes (no OOB)
  int uoff = slice * 48 + l;
  bool act = lane < 48;
  p1_row(in, outF, rp_f, cwf, row, uoff, act, 1.f);
  p1_row(in, outB, rp_b, cwb, row, uoff, act, 1.f);
}

// merged f/b second-order terms: first half of grid = F set, second = B set
__launch_bounds__(256)
__global__ void prop1_ck2x(const uint2v* __restrict__ inF, uint2v* __restrict__ outF,
                           const int* __restrict__ rp_f, const uint2v* __restrict__ cwf,
                           const uint2v* __restrict__ inB, uint2v* __restrict__ outB,
                           const int* __restrict__ rp_b, const uint2v* __restrict__ cwb,
                           int half) {
  bool second = (int)blockIdx.x >= half;
  int b = second ? (int)blockIdx.x - half : (int)blockIdx.x;
  const uint2v* in  = second ? inB  : inF;
  uint2v* out       = second ? outB : outF;
  const int* rp     = second ? rp_b : rp_f;
  const uint2v* cw  = second ? cwb  : cwf;
  int lane = threadIdx.x & 63;
  int wave = threadIdx.x >> 6;
  int slice = b & 7;
  int row = (b >> 3) * 4 + wave;
  int l = lane < 48 ? lane : 47;
  int uoff = slice * 48 + l;
  bool act = lane < 48;
  p1_row(in, out, rp, cw, row, uoff, act, 2.f);
}

// ---- conv2 row: 2-edge 32-lane groups, unroll 4 (8 edges in flight) ----
__device__ __forceinline__ void p2_row(const uint2v* __restrict__ in,
                                       uint2v* __restrict__ out,
                                       const int* __restrict__ rp,
                                       const uint2v* __restrict__ cw,
                                       int row, int slice, int lane, float alpha) {
  int g = lane >> 5;              // group: 0 or 1
  int lg = lane & 31;
  int jb = rp[row], je = rp[row + 1];
  int len = je - jb;
  const uint2v* __restrict__ base = in + slice * 32 + lg;
  float a0 = 0.f, a1 = 0.f, a2 = 0.f, a3 = 0.f;
  int lenM = len & ~7;
  int i = 0;
  for (; i < lenM; i += 8) {
    uint2v e[4], q[4];
    #pragma unroll
    for (int k = 0; k < 4; ++k) e[k] = __builtin_nontemporal_load(&cw[jb + i + 2 * k + g]);
    #pragma unroll
    for (int k = 0; k < 4; ++k) q[k] = base[(size_t)e[k].x * 256];
    #pragma unroll
    for (int k = 0; k < 4; ++k) {
      float w = __uint_as_float(e[k].y);
      a0 += w * bflo(q[k].x); a1 += w * bfhi(q[k].x);
      a2 += w * bflo(q[k].y); a3 += w * bfhi(q[k].y);
    }
  }
  if (i < len) {
    uint2v e[4], q[4];
    float wv[4];
    #pragma unroll
    for (int k = 0; k < 4; ++k) {
      int idx = i + 2 * k + g;
      bool v = idx < len;
      e[k] = __builtin_nontemporal_load(&cw[jb + (v ? idx : 0)]);
      wv[k] = v ? __uint_as_float(e[k].y) : 0.f;
    }
    #pragma unroll
    for (int k = 0; k < 4; ++k) q[k] = base[(size_t)e[k].x * 256];
    #pragma unroll
    for (int k = 0; k < 4; ++k) {
      a0 += wv[k] * bflo(q[k].x); a1 += wv[k] * bfhi(q[k].x);
      a2 += wv[k] * bflo(q[k].y); a3 += wv[k] * bfhi(q[k].y);
    }
  }
  a0 += __shfl_xor(a0, 32); a1 += __shfl_xor(a1, 32);
  a2 += __shfl_xor(a2, 32); a3 += __shfl_xor(a3, 32);
  if (lane < 32) {
    uint2v o; o.x = pack2(alpha * a0, alpha * a1); o.y = pack2(alpha * a2, alpha * a3);
    __builtin_nontemporal_store(o, &out[(size_t)row * 256 + slice * 32 + lg]);
  }
}

__launch_bounds__(256)
__global__ void prop2_dual(const uint2v* __restrict__ in,
                           uint2v* __restrict__ outF, uint2v* __restrict__ outB,
                           const int* __restrict__ rp_f, const uint2v* __restrict__ cwf,
                           const int* __restrict__ rp_b, const uint2v* __restrict__ cwb) {
  int lane = threadIdx.x & 63;
  int wave = threadIdx.x >> 6;
  int slice = blockIdx.x & 7;
  int row = (blockIdx.x >> 3) * 4 + wave;
  p2_row(in, outF, rp_f, cwf, row, slice, lane, 1.f);
  p2_row(in, outB, rp_b, cwb, row, slice, lane, 1.f);
}

__launch_bounds__(256)
__global__ void prop2_ck2x(const uint2v* __restrict__ inF, uint2v* __restrict__ outF,
                           const int* __restrict__ rp_f, const uint2v* __restrict__ cwf,
                           const uint2v* __restrict__ inB, uint2v* __restrict__ outB,
                           const int* __restrict__ rp_b, const uint2v* __restrict__ cwb,
                           int half) {
  bool second = (int)blockIdx.x >= half;
  int b = second ? (int)blockIdx.x - half : (int)blockIdx.x;
  const uint2v* in  = second ? inB  : inF;
  uint2v* out       = second ? outB : outF;
  const int* rp     = second ? rp_b : rp_f;
  const uint2v* cw  = second ? cwb  : cwf;
  int lane = threadIdx.x & 63;
  int wave = threadIdx.x >> 6;
  int slice = b & 7;
  int row = (b >> 3) * 4 + wave;
  p2_row(in, out, rp, cw, row, slice, lane, 2.f);
}

// ---------------- MFMA multi-term GEMM ----------------
// C[128 x NT] per block; 4 waves, each 32 x NT. K = nterms*96.
// Weight columns for loop term t are taken at (t0 + t)*96.
// MFMA layouts (verified): A[m=lane&15][k=quad*8+j]; B[k=quad*8+j][n=lane&15];
//                          C/D col=lane&15, row=quad*4+reg.
// MODE 0: conv1 epilogue: v=sigmoid(bias+acc); col<64 -> rh0=v*h (bf16); else U=v (bf16)
// MODE 1: outp = bias + acc (f32, batch-major)
// MODE 2: cp = outp + acc; c=tanh(tanh(cp)); u from U_in; outp = u*h + (1-u)*c
struct Msrc {
  const uint4* xs[5];
  const uint4* rh[5];
};

template<int NT, int MODE>
__launch_bounds__(256)
__global__ void gemm_mfma(Msrc g, int nterms, int t0,
                          const unsigned short* __restrict__ Wt,
                          const float* __restrict__ bias,
                          float* __restrict__ outp,
                          unsigned short* __restrict__ rh0_s,
                          unsigned short* __restrict__ U_out,
                          const unsigned short* __restrict__ U_in,
                          const float* __restrict__ hglob) {
  constexpr int NJ = NT / 16;
  __shared__ __align__(16) unsigned short As[128][104];   // 13 x 16B per row (odd -> conflict-free)
  __shared__ __align__(16) unsigned short Bs[NT][104];

  int m0 = blockIdx.x * 128;
  int tid = threadIdx.x;
  int wave = tid >> 6;
  int lane = tid & 63;
  int quad = lane >> 4;
  int lm = lane & 15;
  int wm = wave * 32;
  int nodeBase = m0 >> 4;

  f32x4 acc[2][NJ];
  #pragma unroll
  for (int i = 0; i < 2; ++i)
    #pragma unroll
    for (int j = 0; j < NJ; ++j) acc[i][j] = (f32x4){0.f, 0.f, 0.f, 0.f};

  for (int t = 0; t < nterms; ++t) {
    const uint4* xs4 = g.xs[t];
    const uint4* rh4 = g.rh[t];
    if (rh4 == nullptr) {
      const uint4* src = xs4 + (size_t)m0 * 12;
      #pragma unroll
      for (int it = 0; it < 6; ++it) {
        int q = tid + it * 256;
        uint4 v = src[q];
        int row = q / 12, slot = q % 12;
        *(uint4*)&As[row][slot * 8] = v;
      }
    } else {
      #pragma unroll
      for (int it = 0; it < 6; ++it) {
        int q = tid + it * 256;
        int row = q / 12, slot = q % 12;
        int node = nodeBase + (row >> 4);
        int b = row & 15;
        uint4 v; int ci0;
        if (slot < 4) { v = xs4[(size_t)node * 192 + b * 12 + slot]; ci0 = slot * 8; }
        else          { v = rh4[(size_t)node * 128 + b * 8 + (slot - 4)]; ci0 = 32 + (slot - 4) * 8; }
        *(uint4*)&As[row][ci0] = v;
      }
    }
    for (int q = tid; q < NT * 12; q += 256) {
      int n = q / 12, slot = q % 12;
      uint4 v = *(const uint4*)(Wt + (size_t)n * 480 + (t0 + t) * 96 + slot * 8);
      *(uint4*)&Bs[n][slot * 8] = v;
    }
    __syncthreads();

    #pragma unroll
    for (int k32 = 0; k32 < 3; ++k32) {
      int kb = k32 * 32 + quad * 8;
      short8 a0 = *(const short8*)&As[wm + lm][kb];
      short8 a1 = *(const short8*)&As[wm + 16 + lm][kb];
      #pragma unroll
      for (int j = 0; j < NJ; ++j) {
        short8 bf = *(const short8*)&Bs[j * 16 + lm][kb];
        acc[0][j] = __builtin_amdgcn_mfma_f32_16x16x32_bf16(a0, bf, acc[0][j], 0, 0, 0);
        acc[1][j] = __builtin_amdgcn_mfma_f32_16x16x32_bf16(a1, bf, acc[1][j], 0, 0, 0);
      }
    }
    __syncthreads();
  }

  #pragma unroll
  for (int i = 0; i < 2; ++i) {
    #pragma unroll
    for (int j = 0; j < NJ; ++j) {
      int col = j * 16 + lm;
      #pragma unroll
      for (int r = 0; r < 4; ++r) {
        int row = m0 + wm + i * 16 + quad * 4 + r;
        int node = row >> 4, b = row & 15;
        float v = acc[i][j][r];
        if (MODE == 0) {
          float s = 1.f / (1.f + expf(-(bias[col] + v)));
          if (col < COUTn) {
            float hv = hglob[((size_t)b * Nn + node) * COUTn + col];
            rh0_s[(size_t)row * 64 + col] = (unsigned short)f2bfbits(s * hv);
          } else {
            U_out[(size_t)row * 64 + (col - COUTn)] = (unsigned short)f2bfbits(s);
          }
        } else if (MODE == 1) {
          outp[((size_t)b * Nn + node) * COUTn + col] = bias[col] + v;
        } else {
          size_t oa = ((size_t)b * Nn + node) * COUTn + col;
          float cp = outp[oa] + v;
          float c = tanhf(tanhf(cp));
          float u = bf2f(U_in[(size_t)row * 64 + col]);
          outp[oa] = u * hglob[oa] + (1.f - u) * c;
        }
      }
    }
  }
}

// ---------------- host ----------------
extern "C" void kernel_launch(void* const* d_in, const int* in_sizes, int n_in,
                              void* d_out, int out_size, void* d_ws, size_t ws_size,
                              hipStream_t stream) {
  const float* x   = (const float*)d_in[0];
  const float* h   = (const float*)d_in[1];
  const int*   idx = (const int*)d_in[2];
  const float* ew  = (const float*)d_in[3];
  const float* ru_param = (const float*)d_in[4];
  const float* ru_bias  = (const float*)d_in[5];
  const float* c_param  = (const float*)d_in[6];
  const float* c_bias   = (const float*)d_in[7];
  float* outp = (float*)d_out;
  (void)in_sizes; (void)n_in; (void)out_size; (void)ws_size;

  char* ws = (char*)d_ws;
  size_t off = 0;
  auto alloc = [&](size_t bytes) -> char* {
    char* p = ws + off;
    off += (bytes + 255) & ~(size_t)255;
    return p;
  };

  float* deg_f = (float*)alloc(40960);
  float* deg_b = (float*)alloc(40960);
  int*   cnt_f = (int*)alloc(40960);
  int*   cnt_b = (int*)alloc(40960);
  int*   rp_f  = (int*)alloc((Nn + 1) * sizeof(int));
  int*   rp_b  = (int*)alloc((Nn + 1) * sizeof(int));
  int*   cur_f = (int*)alloc(Nn * sizeof(int));
  int*   cur_b = (int*)alloc(Nn * sizeof(int));
  int*   flag  = (int*)alloc(256);
  uint2v* cwf  = (uint2v*)alloc((size_t)En * 8);
  uint2v* cwb  = (uint2v*)alloc((size_t)En * 8);
  unsigned short* Wt1 = (unsigned short*)alloc(128 * 480 * 2);
  unsigned short* Wt2 = (unsigned short*)alloc(64 * 480 * 2);

  unsigned int* A0   = (unsigned int*)alloc((size_t)Nn * WROWU * 4);
  unsigned int* T1f  = (unsigned int*)alloc((size_t)Nn * WROWU * 4);
  unsigned int* T1b  = (unsigned int*)alloc((size_t)Nn * WROWU * 4);
  unsigned int* T2f  = (unsigned int*)alloc((size_t)Nn * WROWU * 4);
  unsigned int* T2b  = (unsigned int*)alloc((size_t)Nn * WROWU * 4);
  unsigned int* rh0  = (unsigned int*)alloc((size_t)Nn * RHU * 4);
  unsigned int* rh1f = (unsigned int*)alloc((size_t)Nn * RHU * 4);
  unsigned int* rh1b = (unsigned int*)alloc((size_t)Nn * RHU * 4);
  unsigned int* Ubuf = (unsigned int*)alloc((size_t)Nn * RHU * 4);
  // ~241 MB total

  hipMemsetAsync(ws, 0, 4 * 40960, stream);
  detect_idx<<<1, 64, 0, stream>>>(idx, flag);
  deg_cnt_kernel<<<En / 256, 256, 0, stream>>>(idx, ew, deg_f, deg_b, cnt_f, cnt_b, flag);
  exscan_two<<<2, 256, 0, stream>>>(cnt_f, cnt_b, rp_f, rp_b, cur_f, cur_b, Nn);
  fill_csr<<<En / 256, 256, 0, stream>>>(idx, ew, deg_f, deg_b, cur_f, cur_b,
                                         cwf, cwb, flag);
  build_wt<<<240, 256, 0, stream>>>(ru_param, c_param, Wt1, Wt2);

  const int gBuild = Nn * WROWU / 256;
  const int gP = (Nn / 4) * 8;   // 4 rows/block (1 per wave) x 8 XCD slices

  // ===== conv1 diffusion =====
  build_x0_ru<<<gBuild, 256, 0, stream>>>(x, h, A0);
  prop1_dual<<<gP, 256, 0, stream>>>(
      (const uint2v*)A0, (uint2v*)T1f, (uint2v*)T1b, rp_f, cwf, rp_b, cwb);
  prop1_ck2x<<<2 * gP, 256, 0, stream>>>(
      (const uint2v*)T1f, (uint2v*)T2f, rp_f, cwf,
      (const uint2v*)T1b, (uint2v*)T2b, rp_b, cwb, gP);

  // ===== conv1 projection: one MFMA GEMM K=480, fused sigmoid + r*h + u-store =====
  Msrc g1;
  g1.xs[0] = (const uint4*)A0;  g1.rh[0] = nullptr;
  g1.xs[1] = (const uint4*)T1f; g1.rh[1] = nullptr;
  g1.xs[2] = (const uint4*)T1b; g1.rh[2] = nullptr;
  g1.xs[3] = (const uint4*)T2f; g1.rh[3] = nullptr;
  g1.xs[4] = (const uint4*)T2b; g1.rh[4] = nullptr;
  gemm_mfma<128, 0><<<MROWS / 128, 256, 0, stream>>>(
      g1, 5, 0, Wt1, ru_bias, nullptr,
      (unsigned short*)rh0, (unsigned short*)Ubuf, nullptr, h);

  // ===== conv2 diffusion on rh =====
  prop2_dual<<<gP, 256, 0, stream>>>(
      (const uint2v*)rh0, (uint2v*)rh1f, (uint2v*)rh1b, rp_f, cwf, rp_b, cwb);

  // conv2 pass A: terms 0,1,2 (weight base t0=0)
  Msrc g2a;
  g2a.xs[0] = (const uint4*)A0;  g2a.rh[0] = (const uint4*)rh0;
  g2a.xs[1] = (const uint4*)T1f; g2a.rh[1] = (const uint4*)rh1f;
  g2a.xs[2] = (const uint4*)T1b; g2a.rh[2] = (const uint4*)rh1b;
  g2a.xs[3] = nullptr; g2a.rh[3] = nullptr;
  g2a.xs[4] = nullptr; g2a.rh[4] = nullptr;
  gemm_mfma<64, 1><<<MROWS / 128, 256, 0, stream>>>(
      g2a, 3, 0, Wt2, c_bias, outp, nullptr, nullptr, nullptr, nullptr);

  // rh second-order terms -> T1f/T1b space (dead after gemm2a), one dispatch
  unsigned int* rh2f = T1f;
  unsigned int* rh2b = T1b;
  prop2_ck2x<<<2 * gP, 256, 0, stream>>>(
      (const uint2v*)rh1f, (uint2v*)rh2f, rp_f, cwf,
      (const uint2v*)rh1b, (uint2v*)rh2b, rp_b, cwb, gP);

  // conv2 pass B: terms 3,4 (weight base t0=3) + fused GRU final
  Msrc g2b;
  g2b.xs[0] = (const uint4*)T2f; g2b.rh[0] = (const uint4*)rh2f;
  g2b.xs[1] = (const uint4*)T2b; g2b.rh[1] = (const uint4*)rh2b;
  g2b.xs[2] = nullptr; g2b.rh[2] = nullptr;
  g2b.xs[3] = nullptr; g2b.rh[3] = nullptr;
  g2b.xs[4] = nullptr; g2b.rh[4] = nullptr;
  gemm_mfma<64, 2><<<MROWS / 128, 256, 0, stream>>>(
      g2b, 2, 3, Wt2, c_bias, outp, nullptr, nullptr,
      (const unsigned short*)Ubuf, h);
}

// Round 6
// 1145.512 us; speedup vs baseline: 1.3591x; 1.3591x over previous
//
#include <hip/hip_runtime.h>
#include <stdint.h>
#include <stddef.h>

#define Bn    16
#define Nn    10000
#define En    320000
#define CIN   32
#define COUTn 64
#define CCn   96
#define WROWU 768           // uints per full node row (16 batches * 96ch / 2)
#define RHU   512           // uints per rh-only node row (16 * 64 / 2)
#define MROWS 160000        // Nn * Bn

typedef __attribute__((ext_vector_type(8))) short short8;   // 8 bf16 = 4 VGPRs
typedef __attribute__((ext_vector_type(4))) float f32x4;

// ---------------- bf16 helpers ----------------
__device__ __forceinline__ float bflo(unsigned int p) { return __uint_as_float(p << 16); }
__device__ __forceinline__ float bfhi(unsigned int p) { return __uint_as_float(p & 0xffff0000u); }
__device__ __forceinline__ float bf2f(unsigned short u) { return __uint_as_float(((unsigned int)u) << 16); }
__device__ __forceinline__ unsigned int f2bfbits(float f) {
  unsigned int x = __float_as_uint(f);
  return (x + 0x7fffu + ((x >> 16) & 1u)) >> 16;
}
__device__ __forceinline__ unsigned int pack2(float lo, float hi) {
  return f2bfbits(lo) | (f2bfbits(hi) << 16);
}

// ---------------- edge_index dtype detection ----------------
__global__ void detect_idx(const int* __restrict__ idx, int* __restrict__ flag) {
  if (threadIdx.x == 0 && blockIdx.x == 0) {
    int is64 = 1;
    for (int i = 1; i < 128; i += 2) {
      if (idx[i] != 0) { is64 = 0; break; }
    }
    flag[0] = is64;
  }
}

__device__ __forceinline__ int gidx(const int* __restrict__ p, int i, int is64) {
  return is64 ? p[2 * (long long)i] : p[i];
}

// ---------------- degree + CSR row counts ----------------
__global__ void deg_cnt_kernel(const int* __restrict__ idx, const float* __restrict__ w,
                               float* __restrict__ deg_f, float* __restrict__ deg_b,
                               int* __restrict__ cnt_f, int* __restrict__ cnt_b,
                               const int* __restrict__ flag) {
  int e = blockIdx.x * 256 + threadIdx.x;
  int is64 = flag[0];
  if (e < En) {
    int s = gidx(idx, e, is64);
    int d = gidx(idx, En + e, is64);
    float we = w[e];
    atomicAdd(&deg_f[s], we);
    atomicAdd(&deg_b[d], we);
    atomicAdd(&cnt_f[d], 1);
    atomicAdd(&cnt_b[s], 1);
  }
}

// ---------------- exclusive scan ----------------
__global__ void exscan_two(const int* __restrict__ cnt_f, const int* __restrict__ cnt_b,
                           int* __restrict__ rp_f, int* __restrict__ rp_b,
                           int* __restrict__ cur_f, int* __restrict__ cur_b, int n) {
  const int* cnt = (blockIdx.x == 0) ? cnt_f : cnt_b;
  int* rp  = (blockIdx.x == 0) ? rp_f  : rp_b;
  int* cur = (blockIdx.x == 0) ? cur_f : cur_b;
  __shared__ int sh[256];
  int t = threadIdx.x;
  int running = 0;
  for (int base = 0; base < n; base += 256) {
    int v = (base + t < n) ? cnt[base + t] : 0;
    sh[t] = v;
    __syncthreads();
    for (int off = 1; off < 256; off <<= 1) {
      int x = (t >= off) ? sh[t - off] : 0;
      __syncthreads();
      sh[t] += x;
      __syncthreads();
    }
    int excl = sh[t] - v;
    if (base + t < n) { rp[base + t] = running + excl; cur[base + t] = running + excl; }
    int total = sh[255];
    __syncthreads();
    running += total;
  }
  if (t == 0) rp[n] = running;
}

// ---------------- CSR fill: packed (col, w) uint2 ----------------
__global__ void fill_csr(const int* __restrict__ idx, const float* __restrict__ w,
                         const float* __restrict__ deg_f, const float* __restrict__ deg_b,
                         int* __restrict__ cur_f, int* __restrict__ cur_b,
                         uint2* __restrict__ cwf, uint2* __restrict__ cwb,
                         const int* __restrict__ flag) {
  int e = blockIdx.x * 256 + threadIdx.x;
  int is64 = flag[0];
  if (e < En) {
    int s = gidx(idx, e, is64);
    int d = gidx(idx, En + e, is64);
    float we = w[e];
    int pf = atomicAdd(&cur_f[d], 1);
    cwf[pf] = make_uint2((unsigned int)s, __float_as_uint(we / deg_f[s]));
    int pb = atomicAdd(&cur_b[s], 1);
    cwb[pb] = make_uint2((unsigned int)d, __float_as_uint(we / deg_b[d]));
  }
}

// ---------------- weight prep: transposed bf16, W0 folded (W0-W3-W4) ----------------
__global__ void build_wt(const float* __restrict__ ru_p, const float* __restrict__ c_p,
                         unsigned short* __restrict__ Wt1, unsigned short* __restrict__ Wt2) {
  int i = blockIdx.x * 256 + threadIdx.x;
  if (i < 128 * 480) {
    int n = i / 480, k = i % 480;
    int t = k / 96, kk = k % 96;
    float v;
    if (t == 0) v = ru_p[(kk * 5 + 0) * 128 + n] - ru_p[(kk * 5 + 3) * 128 + n] - ru_p[(kk * 5 + 4) * 128 + n];
    else        v = ru_p[(kk * 5 + t) * 128 + n];
    Wt1[i] = (unsigned short)f2bfbits(v);
  }
  if (i < 64 * 480) {
    int n = i / 480, k = i % 480;
    int t = k / 96, kk = k % 96;
    float v;
    if (t == 0) v = c_p[(kk * 5 + 0) * 64 + n] - c_p[(kk * 5 + 3) * 64 + n] - c_p[(kk * 5 + 4) * 64 + n];
    else        v = c_p[(kk * 5 + t) * 64 + n];
    Wt2[i] = (unsigned short)f2bfbits(v);
  }
}

// ---------------- X0 builder ----------------
__global__ void build_x0_ru(const float* __restrict__ x, const float* __restrict__ h,
                            unsigned int* __restrict__ X0) {
  long long p = (long long)blockIdx.x * 256 + threadIdx.x;
  int node = (int)(p / WROWU);
  int rem = (int)(p % WROWU);
  int b = rem / 48;
  int ci = (rem % 48) * 2;
  float lo, hi;
  if (ci < CIN) {
    const float* s = x + ((size_t)b * Nn + node) * CIN + ci;
    lo = s[0]; hi = s[1];
  } else {
    const float* s = h + ((size_t)b * Nn + node) * COUTn + (ci - CIN);
    lo = s[0]; hi = s[1];
  }
  X0[p] = pack2(lo, hi);
}

// ---------------- XCD-sliced propagation (R1 structure, unroll-8) ----------------
// Node rows of RU2 uint2 are split into 8 channel slices of SL2 uint2.
// slice = blockIdx & 7 -> with round-robin WG dispatch each XCD only gathers
// its own Nn*SL2*8-byte slice (3.84 MB conv1 / 2.56 MB conv2), L2-resident
// (verified: FETCH 627->175 MB in round 1).
// One wave per row: row bounds via readfirstlane; edge descriptors cw[j] are
// wave-uniform plain loads -> compiler scalarizes to s_load (scalar pipe,
// SGPR results, sequential prefetch). Do NOT make these nontemporal (R5:
// forces vector path, VGPR 12->32, -90% perf). Gathers are exec-masked
// per-lane 8B loads, 8 in flight (R1 had 4; this round's single change).
template<int RU2, int SL2>
__device__ __forceinline__ void prop_row(const uint2* __restrict__ in,
                                         const uint2* __restrict__ cw,
                                         int jb, int je, int u2, bool act,
                                         float& a0, float& a1, float& a2, float& a3) {
  int j = jb;
  for (; j + 8 <= je; j += 8) {
    uint2 e0 = cw[j + 0];
    uint2 e1 = cw[j + 1];
    uint2 e2 = cw[j + 2];
    uint2 e3 = cw[j + 3];
    uint2 e4 = cw[j + 4];
    uint2 e5 = cw[j + 5];
    uint2 e6 = cw[j + 6];
    uint2 e7 = cw[j + 7];
    if (act) {
      uint2 p0 = in[(size_t)e0.x * RU2 + u2];
      uint2 p1 = in[(size_t)e1.x * RU2 + u2];
      uint2 p2 = in[(size_t)e2.x * RU2 + u2];
      uint2 p3 = in[(size_t)e3.x * RU2 + u2];
      uint2 p4 = in[(size_t)e4.x * RU2 + u2];
      uint2 p5 = in[(size_t)e5.x * RU2 + u2];
      uint2 p6 = in[(size_t)e6.x * RU2 + u2];
      uint2 p7 = in[(size_t)e7.x * RU2 + u2];
      float w0 = __uint_as_float(e0.y), w1 = __uint_as_float(e1.y);
      float w2 = __uint_as_float(e2.y), w3 = __uint_as_float(e3.y);
      float w4 = __uint_as_float(e4.y), w5 = __uint_as_float(e5.y);
      float w6 = __uint_as_float(e6.y), w7 = __uint_as_float(e7.y);
      a0 += w0 * bflo(p0.x); a1 += w0 * bfhi(p0.x); a2 += w0 * bflo(p0.y); a3 += w0 * bfhi(p0.y);
      a0 += w1 * bflo(p1.x); a1 += w1 * bfhi(p1.x); a2 += w1 * bflo(p1.y); a3 += w1 * bfhi(p1.y);
      a0 += w2 * bflo(p2.x); a1 += w2 * bfhi(p2.x); a2 += w2 * bflo(p2.y); a3 += w2 * bfhi(p2.y);
      a0 += w3 * bflo(p3.x); a1 += w3 * bfhi(p3.x); a2 += w3 * bflo(p3.y); a3 += w3 * bfhi(p3.y);
      a0 += w4 * bflo(p4.x); a1 += w4 * bfhi(p4.x); a2 += w4 * bflo(p4.y); a3 += w4 * bfhi(p4.y);
      a0 += w5 * bflo(p5.x); a1 += w5 * bfhi(p5.x); a2 += w5 * bflo(p5.y); a3 += w5 * bfhi(p5.y);
      a0 += w6 * bflo(p6.x); a1 += w6 * bfhi(p6.x); a2 += w6 * bflo(p6.y); a3 += w6 * bfhi(p6.y);
      a0 += w7 * bflo(p7.x); a1 += w7 * bfhi(p7.x); a2 += w7 * bflo(p7.y); a3 += w7 * bfhi(p7.y);
    }
  }
  for (; j < je; ++j) {
    uint2 e0 = cw[j];
    if (act) {
      uint2 p0 = in[(size_t)e0.x * RU2 + u2];
      float w0 = __uint_as_float(e0.y);
      a0 += w0 * bflo(p0.x); a1 += w0 * bfhi(p0.x); a2 += w0 * bflo(p0.y); a3 += w0 * bfhi(p0.y);
    }
  }
}

template<int RU2, int SL2>
__launch_bounds__(256)
__global__ void prop_dual_s(const uint2* __restrict__ in,
                            uint2* __restrict__ outF, uint2* __restrict__ outB,
                            const int* __restrict__ rp_f, const uint2* __restrict__ cwf,
                            const int* __restrict__ rp_b, const uint2* __restrict__ cwb) {
  int tid = threadIdx.x;
  int lane = tid & 63;
  int wave = tid >> 6;
  int slice = blockIdx.x & 7;
  int row = ((blockIdx.x >> 3) << 2) + wave;
  int u2 = slice * SL2 + lane;
  bool act = lane < SL2;
  {
    float a0 = 0.f, a1 = 0.f, a2 = 0.f, a3 = 0.f;
    int jb = __builtin_amdgcn_readfirstlane(rp_f[row]);
    int je = __builtin_amdgcn_readfirstlane(rp_f[row + 1]);
    prop_row<RU2, SL2>(in, cwf, jb, je, u2, act, a0, a1, a2, a3);
    if (act) {
      uint2 o; o.x = pack2(a0, a1); o.y = pack2(a2, a3);
      outF[(size_t)row * RU2 + u2] = o;
    }
  }
  {
    float a0 = 0.f, a1 = 0.f, a2 = 0.f, a3 = 0.f;
    int jb = __builtin_amdgcn_readfirstlane(rp_b[row]);
    int je = __builtin_amdgcn_readfirstlane(rp_b[row + 1]);
    prop_row<RU2, SL2>(in, cwb, jb, je, u2, act, a0, a1, a2, a3);
    if (act) {
      uint2 o; o.x = pack2(a0, a1); o.y = pack2(a2, a3);
      outB[(size_t)row * RU2 + u2] = o;
    }
  }
}

template<int RU2, int SL2>
__launch_bounds__(256)
__global__ void prop_ck_s(const uint2* __restrict__ in, uint2* __restrict__ out,
                          const int* __restrict__ rp, const uint2* __restrict__ cw,
                          float alpha) {
  int tid = threadIdx.x;
  int lane = tid & 63;
  int wave = tid >> 6;
  int slice = blockIdx.x & 7;
  int row = ((blockIdx.x >> 3) << 2) + wave;
  int u2 = slice * SL2 + lane;
  bool act = lane < SL2;
  float a0 = 0.f, a1 = 0.f, a2 = 0.f, a3 = 0.f;
  int jb = __builtin_amdgcn_readfirstlane(rp[row]);
  int je = __builtin_amdgcn_readfirstlane(rp[row + 1]);
  prop_row<RU2, SL2>(in, cw, jb, je, u2, act, a0, a1, a2, a3);
  if (act) {
    uint2 o; o.x = pack2(alpha * a0, alpha * a1); o.y = pack2(alpha * a2, alpha * a3);
    out[(size_t)row * RU2 + u2] = o;
  }
}

// ---------------- MFMA multi-term GEMM ----------------
// C[128 x NT] per block; 4 waves, each 32 x NT. K = nterms*96.
// Weight columns for loop term t are taken at (t0 + t)*96.
// MFMA layouts (verified): A[m=lane&15][k=quad*8+j]; B[k=quad*8+j][n=lane&15];
//                          C/D col=lane&15, row=quad*4+reg.
// MODE 0: conv1 epilogue: v=sigmoid(bias+acc); col<64 -> rh0=v*h (bf16); else U=v (bf16)
// MODE 1: outp = bias + acc (f32, batch-major)
// MODE 2: cp = outp + acc; c=tanh(tanh(cp)); u from U_in; outp = u*h + (1-u)*c
struct Msrc {
  const uint4* xs[5];
  const uint4* rh[5];
};

template<int NT, int MODE>
__launch_bounds__(256)
__global__ void gemm_mfma(Msrc g, int nterms, int t0,
                          const unsigned short* __restrict__ Wt,
                          const float* __restrict__ bias,
                          float* __restrict__ outp,
                          unsigned short* __restrict__ rh0_s,
                          unsigned short* __restrict__ U_out,
                          const unsigned short* __restrict__ U_in,
                          const float* __restrict__ hglob) {
  constexpr int NJ = NT / 16;
  __shared__ __align__(16) unsigned short As[128][104];   // 13 x 16B per row (odd -> conflict-free)
  __shared__ __align__(16) unsigned short Bs[NT][104];

  int m0 = blockIdx.x * 128;
  int tid = threadIdx.x;
  int wave = tid >> 6;
  int lane = tid & 63;
  int quad = lane >> 4;
  int lm = lane & 15;
  int wm = wave * 32;
  int nodeBase = m0 >> 4;

  f32x4 acc[2][NJ];
  #pragma unroll
  for (int i = 0; i < 2; ++i)
    #pragma unroll
    for (int j = 0; j < NJ; ++j) acc[i][j] = (f32x4){0.f, 0.f, 0.f, 0.f};

  for (int t = 0; t < nterms; ++t) {
    const uint4* xs4 = g.xs[t];
    const uint4* rh4 = g.rh[t];
    if (rh4 == nullptr) {
      const uint4* src = xs4 + (size_t)m0 * 12;
      #pragma unroll
      for (int it = 0; it < 6; ++it) {
        int q = tid + it * 256;
        uint4 v = src[q];
        int row = q / 12, slot = q % 12;
        *(uint4*)&As[row][slot * 8] = v;
      }
    } else {
      #pragma unroll
      for (int it = 0; it < 6; ++it) {
        int q = tid + it * 256;
        int row = q / 12, slot = q % 12;
        int node = nodeBase + (row >> 4);
        int b = row & 15;
        uint4 v; int ci0;
        if (slot < 4) { v = xs4[(size_t)node * 192 + b * 12 + slot]; ci0 = slot * 8; }
        else          { v = rh4[(size_t)node * 128 + b * 8 + (slot - 4)]; ci0 = 32 + (slot - 4) * 8; }
        *(uint4*)&As[row][ci0] = v;
      }
    }
    for (int q = tid; q < NT * 12; q += 256) {
      int n = q / 12, slot = q % 12;
      uint4 v = *(const uint4*)(Wt + (size_t)n * 480 + (t0 + t) * 96 + slot * 8);
      *(uint4*)&Bs[n][slot * 8] = v;
    }
    __syncthreads();

    #pragma unroll
    for (int k32 = 0; k32 < 3; ++k32) {
      int kb = k32 * 32 + quad * 8;
      short8 a0 = *(const short8*)&As[wm + lm][kb];
      short8 a1 = *(const short8*)&As[wm + 16 + lm][kb];
      #pragma unroll
      for (int j = 0; j < NJ; ++j) {
        short8 bf = *(const short8*)&Bs[j * 16 + lm][kb];
        acc[0][j] = __builtin_amdgcn_mfma_f32_16x16x32_bf16(a0, bf, acc[0][j], 0, 0, 0);
        acc[1][j] = __builtin_amdgcn_mfma_f32_16x16x32_bf16(a1, bf, acc[1][j], 0, 0, 0);
      }
    }
    __syncthreads();
  }

  #pragma unroll
  for (int i = 0; i < 2; ++i) {
    #pragma unroll
    for (int j = 0; j < NJ; ++j) {
      int col = j * 16 + lm;
      #pragma unroll
      for (int r = 0; r < 4; ++r) {
        int row = m0 + wm + i * 16 + quad * 4 + r;
        int node = row >> 4, b = row & 15;
        float v = acc[i][j][r];
        if (MODE == 0) {
          float s = 1.f / (1.f + expf(-(bias[col] + v)));
          if (col < COUTn) {
            float hv = hglob[((size_t)b * Nn + node) * COUTn + col];
            rh0_s[(size_t)row * 64 + col] = (unsigned short)f2bfbits(s * hv);
          } else {
            U_out[(size_t)row * 64 + (col - COUTn)] = (unsigned short)f2bfbits(s);
          }
        } else if (MODE == 1) {
          outp[((size_t)b * Nn + node) * COUTn + col] = bias[col] + v;
        } else {
          size_t oa = ((size_t)b * Nn + node) * COUTn + col;
          float cp = outp[oa] + v;
          float c = tanhf(tanhf(cp));
          float u = bf2f(U_in[(size_t)row * 64 + col]);
          outp[oa] = u * hglob[oa] + (1.f - u) * c;
        }
      }
    }
  }
}

// ---------------- host ----------------
extern "C" void kernel_launch(void* const* d_in, const int* in_sizes, int n_in,
                              void* d_out, int out_size, void* d_ws, size_t ws_size,
                              hipStream_t stream) {
  const float* x   = (const float*)d_in[0];
  const float* h   = (const float*)d_in[1];
  const int*   idx = (const int*)d_in[2];
  const float* ew  = (const float*)d_in[3];
  const float* ru_param = (const float*)d_in[4];
  const float* ru_bias  = (const float*)d_in[5];
  const float* c_param  = (const float*)d_in[6];
  const float* c_bias   = (const float*)d_in[7];
  float* outp = (float*)d_out;
  (void)in_sizes; (void)n_in; (void)out_size; (void)ws_size;

  char* ws = (char*)d_ws;
  size_t off = 0;
  auto alloc = [&](size_t bytes) -> char* {
    char* p = ws + off;
    off += (bytes + 255) & ~(size_t)255;
    return p;
  };

  float* deg_f = (float*)alloc(40960);
  float* deg_b = (float*)alloc(40960);
  int*   cnt_f = (int*)alloc(40960);
  int*   cnt_b = (int*)alloc(40960);
  int*   rp_f  = (int*)alloc((Nn + 1) * sizeof(int));
  int*   rp_b  = (int*)alloc((Nn + 1) * sizeof(int));
  int*   cur_f = (int*)alloc(Nn * sizeof(int));
  int*   cur_b = (int*)alloc(Nn * sizeof(int));
  int*   flag  = (int*)alloc(256);
  uint2* cwf   = (uint2*)alloc((size_t)En * 8);
  uint2* cwb   = (uint2*)alloc((size_t)En * 8);
  unsigned short* Wt1 = (unsigned short*)alloc(128 * 480 * 2);
  unsigned short* Wt2 = (unsigned short*)alloc(64 * 480 * 2);

  unsigned int* A0   = (unsigned int*)alloc((size_t)Nn * WROWU * 4);
  unsigned int* T1f  = (unsigned int*)alloc((size_t)Nn * WROWU * 4);
  unsigned int* T1b  = (unsigned int*)alloc((size_t)Nn * WROWU * 4);
  unsigned int* T2f  = (unsigned int*)alloc((size_t)Nn * WROWU * 4);
  unsigned int* T2b  = (unsigned int*)alloc((size_t)Nn * WROWU * 4);
  unsigned int* rh0  = (unsigned int*)alloc((size_t)Nn * RHU * 4);
  unsigned int* rh1f = (unsigned int*)alloc((size_t)Nn * RHU * 4);
  unsigned int* rh1b = (unsigned int*)alloc((size_t)Nn * RHU * 4);
  unsigned int* Ubuf = (unsigned int*)alloc((size_t)Nn * RHU * 4);
  // ~241 MB total

  hipMemsetAsync(ws, 0, 4 * 40960, stream);
  detect_idx<<<1, 64, 0, stream>>>(idx, flag);
  deg_cnt_kernel<<<En / 256, 256, 0, stream>>>(idx, ew, deg_f, deg_b, cnt_f, cnt_b, flag);
  exscan_two<<<2, 256, 0, stream>>>(cnt_f, cnt_b, rp_f, rp_b, cur_f, cur_b, Nn);
  fill_csr<<<En / 256, 256, 0, stream>>>(idx, ew, deg_f, deg_b, cur_f, cur_b,
                                         cwf, cwb, flag);
  build_wt<<<240, 256, 0, stream>>>(ru_param, c_param, Wt1, Wt2);

  const int gBuild = Nn * WROWU / 256;
  const int gP = (Nn / 4) * 8;   // 4 rows/block (1 per wave) x 8 XCD slices

  // ===== conv1 diffusion (rows of 384 uint2, slices of 48 uint2 = 384 B) =====
  build_x0_ru<<<gBuild, 256, 0, stream>>>(x, h, A0);
  prop_dual_s<384, 48><<<gP, 256, 0, stream>>>(
      (const uint2*)A0, (uint2*)T1f, (uint2*)T1b, rp_f, cwf, rp_b, cwb);
  prop_ck_s<384, 48><<<gP, 256, 0, stream>>>(
      (const uint2*)T1f, (uint2*)T2f, rp_f, cwf, 2.f);
  prop_ck_s<384, 48><<<gP, 256, 0, stream>>>(
      (const uint2*)T1b, (uint2*)T2b, rp_b, cwb, 2.f);

  // ===== conv1 projection: one MFMA GEMM K=480, fused sigmoid + r*h + u-store =====
  Msrc g1;
  g1.xs[0] = (const uint4*)A0;  g1.rh[0] = nullptr;
  g1.xs[1] = (const uint4*)T1f; g1.rh[1] = nullptr;
  g1.xs[2] = (const uint4*)T1b; g1.rh[2] = nullptr;
  g1.xs[3] = (const uint4*)T2f; g1.rh[3] = nullptr;
  g1.xs[4] = (const uint4*)T2b; g1.rh[4] = nullptr;
  gemm_mfma<128, 0><<<MROWS / 128, 256, 0, stream>>>(
      g1, 5, 0, Wt1, ru_bias, nullptr,
      (unsigned short*)rh0, (unsigned short*)Ubuf, nullptr, h);

  // ===== conv2 diffusion on rh (rows of 256 uint2, slices of 32 uint2 = 256 B) =====
  prop_dual_s<256, 32><<<gP, 256, 0, stream>>>(
      (const uint2*)rh0, (uint2*)rh1f, (uint2*)rh1b, rp_f, cwf, rp_b, cwb);

  // conv2 pass A: terms 0,1,2 (weight base t0=0)
  Msrc g2a;
  g2a.xs[0] = (const uint4*)A0;  g2a.rh[0] = (const uint4*)rh0;
  g2a.xs[1] = (const uint4*)T1f; g2a.rh[1] = (const uint4*)rh1f;
  g2a.xs[2] = (const uint4*)T1b; g2a.rh[2] = (const uint4*)rh1b;
  g2a.xs[3] = nullptr; g2a.rh[3] = nullptr;
  g2a.xs[4] = nullptr; g2a.rh[4] = nullptr;
  gemm_mfma<64, 1><<<MROWS / 128, 256, 0, stream>>>(
      g2a, 3, 0, Wt2, c_bias, outp, nullptr, nullptr, nullptr, nullptr);

  // rh second-order terms (reuse rh0/rh1f storage after pass A consumed them)
  prop_ck_s<256, 32><<<gP, 256, 0, stream>>>(
      (const uint2*)rh1f, (uint2*)rh0, rp_f, cwf, 2.f);   // rh2f
  prop_ck_s<256, 32><<<gP, 256, 0, stream>>>(
      (const uint2*)rh1b, (uint2*)rh1f, rp_b, cwb, 2.f);  // rh2b

  // conv2 pass B: terms 3,4 (weight base t0=3) + fused GRU final
  Msrc g2b;
  g2b.xs[0] = (const uint4*)T2f; g2b.rh[0] = (const uint4*)rh0;
  g2b.xs[1] = (const uint4*)T2b; g2b.rh[1] = (const uint4*)rh1f;
  g2b.xs[2] = nullptr; g2b.rh[2] = nullptr;
  g2b.xs[3] = nullptr; g2b.rh[3] = nullptr;
  g2b.xs[4] = nullptr; g2b.rh[4] = nullptr;
  gemm_mfma<64, 2><<<MROWS / 128, 256, 0, stream>>>(
      g2b, 2, 3, Wt2, c_bias, outp, nullptr, nullptr,
      (const unsigned short*)Ubuf, h);
}

// Round 7
// 936.298 us; speedup vs baseline: 1.6627x; 1.2234x over previous
//
#include <hip/hip_runtime.h>
#include <stdint.h>
#include <stddef.h>

#define Bn    16
#define Nn    10000
#define En    320000
#define CIN   32
#define COUTn 64
#define CCn   96
#define WROWU 768           // uints per full node row (16 batches * 96ch / 2)
#define RHU   512           // uints per rh-only node row (16 * 64 / 2)
#define MROWS 160000        // Nn * Bn

typedef __attribute__((ext_vector_type(8))) short short8;   // 8 bf16 = 4 VGPRs
typedef __attribute__((ext_vector_type(4))) float f32x4;
typedef __attribute__((ext_vector_type(4))) unsigned int uint4v;

// ---------------- bf16 helpers ----------------
__device__ __forceinline__ float bflo(unsigned int p) { return __uint_as_float(p << 16); }
__device__ __forceinline__ float bfhi(unsigned int p) { return __uint_as_float(p & 0xffff0000u); }
__device__ __forceinline__ float bf2f(unsigned short u) { return __uint_as_float(((unsigned int)u) << 16); }
__device__ __forceinline__ unsigned int f2bfbits(float f) {
  unsigned int x = __float_as_uint(f);
  return (x + 0x7fffu + ((x >> 16) & 1u)) >> 16;
}
__device__ __forceinline__ unsigned int pack2(float lo, float hi) {
  return f2bfbits(lo) | (f2bfbits(hi) << 16);
}

// ---------------- edge_index dtype detection ----------------
__global__ void detect_idx(const int* __restrict__ idx, int* __restrict__ flag) {
  if (threadIdx.x == 0 && blockIdx.x == 0) {
    int is64 = 1;
    for (int i = 1; i < 128; i += 2) {
      if (idx[i] != 0) { is64 = 0; break; }
    }
    flag[0] = is64;
  }
}

__device__ __forceinline__ int gidx(const int* __restrict__ p, int i, int is64) {
  return is64 ? p[2 * (long long)i] : p[i];
}

// ---------------- degree + CSR row counts ----------------
__global__ void deg_cnt_kernel(const int* __restrict__ idx, const float* __restrict__ w,
                               float* __restrict__ deg_f, float* __restrict__ deg_b,
                               int* __restrict__ cnt_f, int* __restrict__ cnt_b,
                               const int* __restrict__ flag) {
  int e = blockIdx.x * 256 + threadIdx.x;
  int is64 = flag[0];
  if (e < En) {
    int s = gidx(idx, e, is64);
    int d = gidx(idx, En + e, is64);
    float we = w[e];
    atomicAdd(&deg_f[s], we);
    atomicAdd(&deg_b[d], we);
    atomicAdd(&cnt_f[d], 1);
    atomicAdd(&cnt_b[s], 1);
  }
}

// ---------------- exclusive scan ----------------
__global__ void exscan_two(const int* __restrict__ cnt_f, const int* __restrict__ cnt_b,
                           int* __restrict__ rp_f, int* __restrict__ rp_b,
                           int* __restrict__ cur_f, int* __restrict__ cur_b, int n) {
  const int* cnt = (blockIdx.x == 0) ? cnt_f : cnt_b;
  int* rp  = (blockIdx.x == 0) ? rp_f  : rp_b;
  int* cur = (blockIdx.x == 0) ? cur_f : cur_b;
  __shared__ int sh[256];
  int t = threadIdx.x;
  int running = 0;
  for (int base = 0; base < n; base += 256) {
    int v = (base + t < n) ? cnt[base + t] : 0;
    sh[t] = v;
    __syncthreads();
    for (int off = 1; off < 256; off <<= 1) {
      int x = (t >= off) ? sh[t - off] : 0;
      __syncthreads();
      sh[t] += x;
      __syncthreads();
    }
    int excl = sh[t] - v;
    if (base + t < n) { rp[base + t] = running + excl; cur[base + t] = running + excl; }
    int total = sh[255];
    __syncthreads();
    running += total;
  }
  if (t == 0) rp[n] = running;
}

// ---------------- CSR fill: packed (col, w) uint2 ----------------
__global__ void fill_csr(const int* __restrict__ idx, const float* __restrict__ w,
                         const float* __restrict__ deg_f, const float* __restrict__ deg_b,
                         int* __restrict__ cur_f, int* __restrict__ cur_b,
                         uint2* __restrict__ cwf, uint2* __restrict__ cwb,
                         const int* __restrict__ flag) {
  int e = blockIdx.x * 256 + threadIdx.x;
  int is64 = flag[0];
  if (e < En) {
    int s = gidx(idx, e, is64);
    int d = gidx(idx, En + e, is64);
    float we = w[e];
    int pf = atomicAdd(&cur_f[d], 1);
    cwf[pf] = make_uint2((unsigned int)s, __float_as_uint(we / deg_f[s]));
    int pb = atomicAdd(&cur_b[s], 1);
    cwb[pb] = make_uint2((unsigned int)d, __float_as_uint(we / deg_b[d]));
  }
}

// ---------------- weight prep: transposed bf16, W0 folded (W0-W3-W4) ----------------
__global__ void build_wt(const float* __restrict__ ru_p, const float* __restrict__ c_p,
                         unsigned short* __restrict__ Wt1, unsigned short* __restrict__ Wt2) {
  int i = blockIdx.x * 256 + threadIdx.x;
  if (i < 128 * 480) {
    int n = i / 480, k = i % 480;
    int t = k / 96, kk = k % 96;
    float v;
    if (t == 0) v = ru_p[(kk * 5 + 0) * 128 + n] - ru_p[(kk * 5 + 3) * 128 + n] - ru_p[(kk * 5 + 4) * 128 + n];
    else        v = ru_p[(kk * 5 + t) * 128 + n];
    Wt1[i] = (unsigned short)f2bfbits(v);
  }
  if (i < 64 * 480) {
    int n = i / 480, k = i % 480;
    int t = k / 96, kk = k % 96;
    float v;
    if (t == 0) v = c_p[(kk * 5 + 0) * 64 + n] - c_p[(kk * 5 + 3) * 64 + n] - c_p[(kk * 5 + 4) * 64 + n];
    else        v = c_p[(kk * 5 + t) * 64 + n];
    Wt2[i] = (unsigned short)f2bfbits(v);
  }
}

// ---------------- X0 builder ----------------
__global__ void build_x0_ru(const float* __restrict__ x, const float* __restrict__ h,
                            unsigned int* __restrict__ X0) {
  long long p = (long long)blockIdx.x * 256 + threadIdx.x;
  int node = (int)(p / WROWU);
  int rem = (int)(p % WROWU);
  int b = rem / 48;
  int ci = (rem % 48) * 2;
  float lo, hi;
  if (ci < CIN) {
    const float* s = x + ((size_t)b * Nn + node) * CIN + ci;
    lo = s[0]; hi = s[1];
  } else {
    const float* s = h + ((size_t)b * Nn + node) * COUTn + (ci - CIN);
    lo = s[0]; hi = s[1];
  }
  X0[p] = pack2(lo, hi);
}

// ---------------- XCD-sliced propagation, multi-edge waves, scalar descriptors ----
// Node rows of RU4 uint4 are split into 8 channel slices of ACT uint4.
// slice = blockIdx & 7 -> each XCD gathers only its own 3.84/2.56 MB slice,
// L2-resident (verified FETCH 627->175 MB in R1).
// One row per wave; EPW edges per gather instruction: lane groups of 64/EPW
// lanes each gather one edge's 16B-per-lane slice. Edge descriptors are
// loaded at WAVE-UNIFORM indices (-> s_load scalar pipe; R3/R4/R5 lesson:
// per-lane or nontemporal descriptor loads force the vector path and lose
// up to 2x), then per-lane selected by group id. 4 gathers in flight
// (R6 showed MLP>=4 is saturated). Cross-group shfl_xor reduce at the end.
template<int RU4, int ACT, int EPW>
__device__ __forceinline__ void prop_rowX(const uint4v* __restrict__ in,
                                          uint4v* __restrict__ out,
                                          const int* __restrict__ rp,
                                          const uint2* __restrict__ cw,
                                          int row, int slice, int lane, float alpha) {
  constexpr int GSZ = 64 / EPW;
  int grp = (EPW == 2) ? (lane >> 5) : (lane >> 4);
  int lg = lane & (GSZ - 1);
  int lgc = (lg < ACT) ? lg : 0;       // pad lanes duplicate lane 0's line (coalesced, free)
  const uint4v* __restrict__ base = in + slice * ACT + lgc;
  int jb = __builtin_amdgcn_readfirstlane(rp[row]);
  int je = __builtin_amdgcn_readfirstlane(rp[row + 1]);
  int len = je - jb;

  float a[8];
  #pragma unroll
  for (int k = 0; k < 8; ++k) a[k] = 0.f;

  constexpr int STEP = 4 * EPW;        // 4 gather instrs in flight per wave
  int i = jb;
  int eM = jb + (len / STEP) * STEP;
  for (; i < eM; i += STEP) {
    #pragma unroll
    for (int k = 0; k < 4; ++k) {
      unsigned int col; float w;
      {
        uint2 e0 = cw[i + k * EPW + 0];
        uint2 e1 = cw[i + k * EPW + 1];
        col = (grp & 1) ? e1.x : e0.x;
        w = __uint_as_float((grp & 1) ? e1.y : e0.y);
        if (EPW == 4) {
          uint2 e2 = cw[i + k * EPW + 2];
          uint2 e3 = cw[i + k * EPW + 3];
          unsigned int colB = (grp & 1) ? e3.x : e2.x;
          float wB = __uint_as_float((grp & 1) ? e3.y : e2.y);
          col = (grp & 2) ? colB : col;
          w = (grp & 2) ? wB : w;
        }
      }
      uint4v q = base[(size_t)col * RU4];
      a[0] += w * bflo(q.x); a[1] += w * bfhi(q.x);
      a[2] += w * bflo(q.y); a[3] += w * bfhi(q.y);
      a[4] += w * bflo(q.z); a[5] += w * bfhi(q.z);
      a[6] += w * bflo(q.w); a[7] += w * bfhi(q.w);
    }
  }
  // masked tail, EPW edges per step (clamped uniform descriptor indices)
  for (; i < je; i += EPW) {
    unsigned int col; float w;
    {
      uint2 e0 = cw[i + 0];
      uint2 e1 = cw[(i + 1 < je) ? i + 1 : i];
      col = (grp & 1) ? e1.x : e0.x;
      w = __uint_as_float((grp & 1) ? e1.y : e0.y);
      if (EPW == 4) {
        uint2 e2 = cw[(i + 2 < je) ? i + 2 : i];
        uint2 e3 = cw[(i + 3 < je) ? i + 3 : i];
        unsigned int colB = (grp & 1) ? e3.x : e2.x;
        float wB = __uint_as_float((grp & 1) ? e3.y : e2.y);
        col = (grp & 2) ? colB : col;
        w = (grp & 2) ? wB : w;
      }
    }
    if (i + grp >= je) w = 0.f;        // invalid lanes contribute 0 (clamped addr is safe)
    uint4v q = base[(size_t)col * RU4];
    a[0] += w * bflo(q.x); a[1] += w * bfhi(q.x);
    a[2] += w * bflo(q.y); a[3] += w * bfhi(q.y);
    a[4] += w * bflo(q.z); a[5] += w * bfhi(q.z);
    a[6] += w * bflo(q.w); a[7] += w * bfhi(q.w);
  }

  // cross-group reduce (idle-lane pairs stay among idle lanes; discarded)
  #pragma unroll
  for (int k = 0; k < 8; ++k) {
    if (EPW == 4) a[k] += __shfl_xor(a[k], 16);
    a[k] += __shfl_xor(a[k], 32);
  }

  if (grp == 0 && lg < ACT) {
    uint4v o;
    o.x = pack2(alpha * a[0], alpha * a[1]);
    o.y = pack2(alpha * a[2], alpha * a[3]);
    o.z = pack2(alpha * a[4], alpha * a[5]);
    o.w = pack2(alpha * a[6], alpha * a[7]);
    out[(size_t)row * RU4 + slice * ACT + lg] = o;
  }
}

template<int RU4, int ACT, int EPW>
__launch_bounds__(256)
__global__ void prop_dualX(const uint4v* __restrict__ in,
                           uint4v* __restrict__ outF, uint4v* __restrict__ outB,
                           const int* __restrict__ rp_f, const uint2* __restrict__ cwf,
                           const int* __restrict__ rp_b, const uint2* __restrict__ cwb) {
  int lane = threadIdx.x & 63;
  int wave = threadIdx.x >> 6;
  int slice = blockIdx.x & 7;
  int row = ((blockIdx.x >> 3) << 2) + wave;
  prop_rowX<RU4, ACT, EPW>(in, outF, rp_f, cwf, row, slice, lane, 1.f);
  prop_rowX<RU4, ACT, EPW>(in, outB, rp_b, cwb, row, slice, lane, 1.f);
}

template<int RU4, int ACT, int EPW>
__launch_bounds__(256)
__global__ void prop_ckX(const uint4v* __restrict__ in, uint4v* __restrict__ out,
                         const int* __restrict__ rp, const uint2* __restrict__ cw,
                         float alpha) {
  int lane = threadIdx.x & 63;
  int wave = threadIdx.x >> 6;
  int slice = blockIdx.x & 7;
  int row = ((blockIdx.x >> 3) << 2) + wave;
  prop_rowX<RU4, ACT, EPW>(in, out, rp, cw, row, slice, lane, alpha);
}

// ---------------- MFMA multi-term GEMM ----------------
// C[128 x NT] per block; 4 waves, each 32 x NT. K = nterms*96.
// Weight columns for loop term t are taken at (t0 + t)*96.
// MFMA layouts (verified): A[m=lane&15][k=quad*8+j]; B[k=quad*8+j][n=lane&15];
//                          C/D col=lane&15, row=quad*4+reg.
// MODE 0: conv1 epilogue: v=sigmoid(bias+acc); col<64 -> rh0=v*h (bf16); else U=v (bf16)
// MODE 1: outp = bias + acc (f32, batch-major)
// MODE 2: cp = outp + acc; c=tanh(tanh(cp)); u from U_in; outp = u*h + (1-u)*c
struct Msrc {
  const uint4* xs[5];
  const uint4* rh[5];
};

template<int NT, int MODE>
__launch_bounds__(256)
__global__ void gemm_mfma(Msrc g, int nterms, int t0,
                          const unsigned short* __restrict__ Wt,
                          const float* __restrict__ bias,
                          float* __restrict__ outp,
                          unsigned short* __restrict__ rh0_s,
                          unsigned short* __restrict__ U_out,
                          const unsigned short* __restrict__ U_in,
                          const float* __restrict__ hglob) {
  constexpr int NJ = NT / 16;
  __shared__ __align__(16) unsigned short As[128][104];   // 13 x 16B per row (odd -> conflict-free)
  __shared__ __align__(16) unsigned short Bs[NT][104];

  int m0 = blockIdx.x * 128;
  int tid = threadIdx.x;
  int wave = tid >> 6;
  int lane = tid & 63;
  int quad = lane >> 4;
  int lm = lane & 15;
  int wm = wave * 32;
  int nodeBase = m0 >> 4;

  f32x4 acc[2][NJ];
  #pragma unroll
  for (int i = 0; i < 2; ++i)
    #pragma unroll
    for (int j = 0; j < NJ; ++j) acc[i][j] = (f32x4){0.f, 0.f, 0.f, 0.f};

  for (int t = 0; t < nterms; ++t) {
    const uint4* xs4 = g.xs[t];
    const uint4* rh4 = g.rh[t];
    if (rh4 == nullptr) {
      const uint4* src = xs4 + (size_t)m0 * 12;
      #pragma unroll
      for (int it = 0; it < 6; ++it) {
        int q = tid + it * 256;
        uint4 v = src[q];
        int row = q / 12, slot = q % 12;
        *(uint4*)&As[row][slot * 8] = v;
      }
    } else {
      #pragma unroll
      for (int it = 0; it < 6; ++it) {
        int q = tid + it * 256;
        int row = q / 12, slot = q % 12;
        int node = nodeBase + (row >> 4);
        int b = row & 15;
        uint4 v; int ci0;
        if (slot < 4) { v = xs4[(size_t)node * 192 + b * 12 + slot]; ci0 = slot * 8; }
        else          { v = rh4[(size_t)node * 128 + b * 8 + (slot - 4)]; ci0 = 32 + (slot - 4) * 8; }
        *(uint4*)&As[row][ci0] = v;
      }
    }
    for (int q = tid; q < NT * 12; q += 256) {
      int n = q / 12, slot = q % 12;
      uint4 v = *(const uint4*)(Wt + (size_t)n * 480 + (t0 + t) * 96 + slot * 8);
      *(uint4*)&Bs[n][slot * 8] = v;
    }
    __syncthreads();

    #pragma unroll
    for (int k32 = 0; k32 < 3; ++k32) {
      int kb = k32 * 32 + quad * 8;
      short8 a0 = *(const short8*)&As[wm + lm][kb];
      short8 a1 = *(const short8*)&As[wm + 16 + lm][kb];
      #pragma unroll
      for (int j = 0; j < NJ; ++j) {
        short8 bf = *(const short8*)&Bs[j * 16 + lm][kb];
        acc[0][j] = __builtin_amdgcn_mfma_f32_16x16x32_bf16(a0, bf, acc[0][j], 0, 0, 0);
        acc[1][j] = __builtin_amdgcn_mfma_f32_16x16x32_bf16(a1, bf, acc[1][j], 0, 0, 0);
      }
    }
    __syncthreads();
  }

  #pragma unroll
  for (int i = 0; i < 2; ++i) {
    #pragma unroll
    for (int j = 0; j < NJ; ++j) {
      int col = j * 16 + lm;
      #pragma unroll
      for (int r = 0; r < 4; ++r) {
        int row = m0 + wm + i * 16 + quad * 4 + r;
        int node = row >> 4, b = row & 15;
        float v = acc[i][j][r];
        if (MODE == 0) {
          float s = 1.f / (1.f + expf(-(bias[col] + v)));
          if (col < COUTn) {
            float hv = hglob[((size_t)b * Nn + node) * COUTn + col];
            rh0_s[(size_t)row * 64 + col] = (unsigned short)f2bfbits(s * hv);
          } else {
            U_out[(size_t)row * 64 + (col - COUTn)] = (unsigned short)f2bfbits(s);
          }
        } else if (MODE == 1) {
          outp[((size_t)b * Nn + node) * COUTn + col] = bias[col] + v;
        } else {
          size_t oa = ((size_t)b * Nn + node) * COUTn + col;
          float cp = outp[oa] + v;
          float c = tanhf(tanhf(cp));
          float u = bf2f(U_in[(size_t)row * 64 + col]);
          outp[oa] = u * hglob[oa] + (1.f - u) * c;
        }
      }
    }
  }
}

// ---------------- host ----------------
extern "C" void kernel_launch(void* const* d_in, const int* in_sizes, int n_in,
                              void* d_out, int out_size, void* d_ws, size_t ws_size,
                              hipStream_t stream) {
  const float* x   = (const float*)d_in[0];
  const float* h   = (const float*)d_in[1];
  const int*   idx = (const int*)d_in[2];
  const float* ew  = (const float*)d_in[3];
  const float* ru_param = (const float*)d_in[4];
  const float* ru_bias  = (const float*)d_in[5];
  const float* c_param  = (const float*)d_in[6];
  const float* c_bias   = (const float*)d_in[7];
  float* outp = (float*)d_out;
  (void)in_sizes; (void)n_in; (void)out_size; (void)ws_size;

  char* ws = (char*)d_ws;
  size_t off = 0;
  auto alloc = [&](size_t bytes) -> char* {
    char* p = ws + off;
    off += (bytes + 255) & ~(size_t)255;
    return p;
  };

  float* deg_f = (float*)alloc(40960);
  float* deg_b = (float*)alloc(40960);
  int*   cnt_f = (int*)alloc(40960);
  int*   cnt_b = (int*)alloc(40960);
  int*   rp_f  = (int*)alloc((Nn + 1) * sizeof(int));
  int*   rp_b  = (int*)alloc((Nn + 1) * sizeof(int));
  int*   cur_f = (int*)alloc(Nn * sizeof(int));
  int*   cur_b = (int*)alloc(Nn * sizeof(int));
  int*   flag  = (int*)alloc(256);
  uint2* cwf   = (uint2*)alloc((size_t)En * 8);
  uint2* cwb   = (uint2*)alloc((size_t)En * 8);
  unsigned short* Wt1 = (unsigned short*)alloc(128 * 480 * 2);
  unsigned short* Wt2 = (unsigned short*)alloc(64 * 480 * 2);

  unsigned int* A0   = (unsigned int*)alloc((size_t)Nn * WROWU * 4);
  unsigned int* T1f  = (unsigned int*)alloc((size_t)Nn * WROWU * 4);
  unsigned int* T1b  = (unsigned int*)alloc((size_t)Nn * WROWU * 4);
  unsigned int* T2f  = (unsigned int*)alloc((size_t)Nn * WROWU * 4);
  unsigned int* T2b  = (unsigned int*)alloc((size_t)Nn * WROWU * 4);
  unsigned int* rh0  = (unsigned int*)alloc((size_t)Nn * RHU * 4);
  unsigned int* rh1f = (unsigned int*)alloc((size_t)Nn * RHU * 4);
  unsigned int* rh1b = (unsigned int*)alloc((size_t)Nn * RHU * 4);
  unsigned int* Ubuf = (unsigned int*)alloc((size_t)Nn * RHU * 4);
  // ~241 MB total

  hipMemsetAsync(ws, 0, 4 * 40960, stream);
  detect_idx<<<1, 64, 0, stream>>>(idx, flag);
  deg_cnt_kernel<<<En / 256, 256, 0, stream>>>(idx, ew, deg_f, deg_b, cnt_f, cnt_b, flag);
  exscan_two<<<2, 256, 0, stream>>>(cnt_f, cnt_b, rp_f, rp_b, cur_f, cur_b, Nn);
  fill_csr<<<En / 256, 256, 0, stream>>>(idx, ew, deg_f, deg_b, cur_f, cur_b,
                                         cwf, cwb, flag);
  build_wt<<<240, 256, 0, stream>>>(ru_param, c_param, Wt1, Wt2);

  const int gBuild = Nn * WROWU / 256;
  const int gP = (Nn / 4) * 8;   // 4 rows/block (1 per wave) x 8 XCD slices

  // ===== conv1 diffusion (rows of 192 uint4, slices of 24 uint4, 2 edges/gather) =====
  build_x0_ru<<<gBuild, 256, 0, stream>>>(x, h, A0);
  prop_dualX<192, 24, 2><<<gP, 256, 0, stream>>>(
      (const uint4v*)A0, (uint4v*)T1f, (uint4v*)T1b, rp_f, cwf, rp_b, cwb);
  prop_ckX<192, 24, 2><<<gP, 256, 0, stream>>>(
      (const uint4v*)T1f, (uint4v*)T2f, rp_f, cwf, 2.f);
  prop_ckX<192, 24, 2><<<gP, 256, 0, stream>>>(
      (const uint4v*)T1b, (uint4v*)T2b, rp_b, cwb, 2.f);

  // ===== conv1 projection: one MFMA GEMM K=480, fused sigmoid + r*h + u-store =====
  Msrc g1;
  g1.xs[0] = (const uint4*)A0;  g1.rh[0] = nullptr;
  g1.xs[1] = (const uint4*)T1f; g1.rh[1] = nullptr;
  g1.xs[2] = (const uint4*)T1b; g1.rh[2] = nullptr;
  g1.xs[3] = (const uint4*)T2f; g1.rh[3] = nullptr;
  g1.xs[4] = (const uint4*)T2b; g1.rh[4] = nullptr;
  gemm_mfma<128, 0><<<MROWS / 128, 256, 0, stream>>>(
      g1, 5, 0, Wt1, ru_bias, nullptr,
      (unsigned short*)rh0, (unsigned short*)Ubuf, nullptr, h);

  // ===== conv2 diffusion on rh (rows of 128 uint4, slices of 16 uint4, 4 edges/gather) =====
  prop_dualX<128, 16, 4><<<gP, 256, 0, stream>>>(
      (const uint4v*)rh0, (uint4v*)rh1f, (uint4v*)rh1b, rp_f, cwf, rp_b, cwb);

  // conv2 pass A: terms 0,1,2 (weight base t0=0)
  Msrc g2a;
  g2a.xs[0] = (const uint4*)A0;  g2a.rh[0] = (const uint4*)rh0;
  g2a.xs[1] = (const uint4*)T1f; g2a.rh[1] = (const uint4*)rh1f;
  g2a.xs[2] = (const uint4*)T1b; g2a.rh[2] = (const uint4*)rh1b;
  g2a.xs[3] = nullptr; g2a.rh[3] = nullptr;
  g2a.xs[4] = nullptr; g2a.rh[4] = nullptr;
  gemm_mfma<64, 1><<<MROWS / 128, 256, 0, stream>>>(
      g2a, 3, 0, Wt2, c_bias, outp, nullptr, nullptr, nullptr, nullptr);

  // rh second-order terms (reuse rh0/rh1f storage after pass A consumed them)
  prop_ckX<128, 16, 4><<<gP, 256, 0, stream>>>(
      (const uint4v*)rh1f, (uint4v*)rh0, rp_f, cwf, 2.f);   // rh2f
  prop_ckX<128, 16, 4><<<gP, 256, 0, stream>>>(
      (const uint4v*)rh1b, (uint4v*)rh1f, rp_b, cwb, 2.f);  // rh2b

  // conv2 pass B: terms 3,4 (weight base t0=3) + fused GRU final
  Msrc g2b;
  g2b.xs[0] = (const uint4*)T2f; g2b.rh[0] = (const uint4*)rh0;
  g2b.xs[1] = (const uint4*)T2b; g2b.rh[1] = (const uint4*)rh1f;
  g2b.xs[2] = nullptr; g2b.rh[2] = nullptr;
  g2b.xs[3] = nullptr; g2b.rh[3] = nullptr;
  g2b.xs[4] = nullptr; g2b.rh[4] = nullptr;
  gemm_mfma<64, 2><<<MROWS / 128, 256, 0, stream>>>(
      g2b, 2, 3, Wt2, c_bias, outp, nullptr, nullptr,
      (const unsigned short*)Ubuf, h);
}

// Round 8
// 922.677 us; speedup vs baseline: 1.6873x; 1.0148x over previous
//
#include <hip/hip_runtime.h>
#include <stdint.h>
#include <stddef.h>

#define Bn    16
#define Nn    10000
#define En    320000
#define CIN   32
#define COUTn 64
#define CCn   96
#define WROWU 768           // uints per full node row (16 batches * 96ch / 2)
#define RHU   512           // uints per rh-only node row (16 * 64 / 2)
#define MROWS 160000        // Nn * Bn

typedef __attribute__((ext_vector_type(8))) short short8;   // 8 bf16 = 4 VGPRs
typedef __attribute__((ext_vector_type(4))) float f32x4;
typedef __attribute__((ext_vector_type(2))) float f32x2;
typedef __attribute__((ext_vector_type(4))) unsigned int uint4v;

// ---------------- bf16 helpers ----------------
__device__ __forceinline__ float bflo(unsigned int p) { return __uint_as_float(p << 16); }
__device__ __forceinline__ float bfhi(unsigned int p) { return __uint_as_float(p & 0xffff0000u); }
__device__ __forceinline__ float bf2f(unsigned short u) { return __uint_as_float(((unsigned int)u) << 16); }
__device__ __forceinline__ unsigned int f2bfbits(float f) {
  unsigned int x = __float_as_uint(f);
  return (x + 0x7fffu + ((x >> 16) & 1u)) >> 16;
}
__device__ __forceinline__ unsigned int pack2(float lo, float hi) {
  return f2bfbits(lo) | (f2bfbits(hi) << 16);
}

// ---------------- edge_index dtype detection ----------------
__global__ void detect_idx(const int* __restrict__ idx, int* __restrict__ flag) {
  if (threadIdx.x == 0 && blockIdx.x == 0) {
    int is64 = 1;
    for (int i = 1; i < 128; i += 2) {
      if (idx[i] != 0) { is64 = 0; break; }
    }
    flag[0] = is64;
  }
}

__device__ __forceinline__ int gidx(const int* __restrict__ p, int i, int is64) {
  return is64 ? p[2 * (long long)i] : p[i];
}

// ---------------- degree + CSR row counts ----------------
__global__ void deg_cnt_kernel(const int* __restrict__ idx, const float* __restrict__ w,
                               float* __restrict__ deg_f, float* __restrict__ deg_b,
                               int* __restrict__ cnt_f, int* __restrict__ cnt_b,
                               const int* __restrict__ flag) {
  int e = blockIdx.x * 256 + threadIdx.x;
  int is64 = flag[0];
  if (e < En) {
    int s = gidx(idx, e, is64);
    int d = gidx(idx, En + e, is64);
    float we = w[e];
    atomicAdd(&deg_f[s], we);
    atomicAdd(&deg_b[d], we);
    atomicAdd(&cnt_f[d], 1);
    atomicAdd(&cnt_b[s], 1);
  }
}

// ---------------- exclusive scan ----------------
__global__ void exscan_two(const int* __restrict__ cnt_f, const int* __restrict__ cnt_b,
                           int* __restrict__ rp_f, int* __restrict__ rp_b,
                           int* __restrict__ cur_f, int* __restrict__ cur_b, int n) {
  const int* cnt = (blockIdx.x == 0) ? cnt_f : cnt_b;
  int* rp  = (blockIdx.x == 0) ? rp_f  : rp_b;
  int* cur = (blockIdx.x == 0) ? cur_f : cur_b;
  __shared__ int sh[256];
  int t = threadIdx.x;
  int running = 0;
  for (int base = 0; base < n; base += 256) {
    int v = (base + t < n) ? cnt[base + t] : 0;
    sh[t] = v;
    __syncthreads();
    for (int off = 1; off < 256; off <<= 1) {
      int x = (t >= off) ? sh[t - off] : 0;
      __syncthreads();
      sh[t] += x;
      __syncthreads();
    }
    int excl = sh[t] - v;
    if (base + t < n) { rp[base + t] = running + excl; cur[base + t] = running + excl; }
    int total = sh[255];
    __syncthreads();
    running += total;
  }
  if (t == 0) rp[n] = running;
}

// ---------------- CSR fill: packed (col, w) uint2 ----------------
__global__ void fill_csr(const int* __restrict__ idx, const float* __restrict__ w,
                         const float* __restrict__ deg_f, const float* __restrict__ deg_b,
                         int* __restrict__ cur_f, int* __restrict__ cur_b,
                         uint2* __restrict__ cwf, uint2* __restrict__ cwb,
                         const int* __restrict__ flag) {
  int e = blockIdx.x * 256 + threadIdx.x;
  int is64 = flag[0];
  if (e < En) {
    int s = gidx(idx, e, is64);
    int d = gidx(idx, En + e, is64);
    float we = w[e];
    int pf = atomicAdd(&cur_f[d], 1);
    cwf[pf] = make_uint2((unsigned int)s, __float_as_uint(we / deg_f[s]));
    int pb = atomicAdd(&cur_b[s], 1);
    cwb[pb] = make_uint2((unsigned int)d, __float_as_uint(we / deg_b[d]));
  }
}

// ---------------- weight prep: transposed bf16, W0 folded (W0-W3-W4) ----------------
__global__ void build_wt(const float* __restrict__ ru_p, const float* __restrict__ c_p,
                         unsigned short* __restrict__ Wt1, unsigned short* __restrict__ Wt2) {
  int i = blockIdx.x * 256 + threadIdx.x;
  if (i < 128 * 480) {
    int n = i / 480, k = i % 480;
    int t = k / 96, kk = k % 96;
    float v;
    if (t == 0) v = ru_p[(kk * 5 + 0) * 128 + n] - ru_p[(kk * 5 + 3) * 128 + n] - ru_p[(kk * 5 + 4) * 128 + n];
    else        v = ru_p[(kk * 5 + t) * 128 + n];
    Wt1[i] = (unsigned short)f2bfbits(v);
  }
  if (i < 64 * 480) {
    int n = i / 480, k = i % 480;
    int t = k / 96, kk = k % 96;
    float v;
    if (t == 0) v = c_p[(kk * 5 + 0) * 64 + n] - c_p[(kk * 5 + 3) * 64 + n] - c_p[(kk * 5 + 4) * 64 + n];
    else        v = c_p[(kk * 5 + t) * 64 + n];
    Wt2[i] = (unsigned short)f2bfbits(v);
  }
}

// ---------------- X0 builder ----------------
__global__ void build_x0_ru(const float* __restrict__ x, const float* __restrict__ h,
                            unsigned int* __restrict__ X0) {
  long long p = (long long)blockIdx.x * 256 + threadIdx.x;
  int node = (int)(p / WROWU);
  int rem = (int)(p % WROWU);
  int b = rem / 48;
  int ci = (rem % 48) * 2;
  float lo, hi;
  if (ci < CIN) {
    const float* s = x + ((size_t)b * Nn + node) * CIN + ci;
    lo = s[0]; hi = s[1];
  } else {
    const float* s = h + ((size_t)b * Nn + node) * COUTn + (ci - CIN);
    lo = s[0]; hi = s[1];
  }
  X0[p] = pack2(lo, hi);
}

// ---------------- XCD-sliced propagation, multi-edge waves, scalar descriptors ----
// Node rows of RU4 uint4 are split into 8 channel slices of ACT uint4.
// slice = blockIdx & 7 -> each XCD gathers only its own 3.84/2.56 MB slice,
// L2-resident (verified FETCH 627->175 MB in R1).
// One row per wave; EPW edges per gather instruction (R7: -25% total).
// Edge descriptors at WAVE-UNIFORM indices (-> s_load scalar pipe; R3/R4/R5:
// per-lane/nontemporal descriptor loads force the vector path, up to -2x),
// then per-lane cndmask-selected by group id.
// R8 (this round, kernel VALU-bound at 92% VALUBusy):
//  - 32-bit SADDR addressing: off = umul24(col, ROWBYTES) + laneByte (1 mad)
//    replaces the (size_t) 64-bit add chain (~3 VALU/edge-pair saved).
//  - packed f32 accumulation (float2 -> v_pk_fma_f32): 8 -> 4 FMAs/edge-pair.
template<int RU4, int ACT, int EPW>
__device__ __forceinline__ void prop_rowX(const uint4v* __restrict__ in,
                                          uint4v* __restrict__ out,
                                          const int* __restrict__ rp,
                                          const uint2* __restrict__ cw,
                                          int row, int slice, int lane, float alpha) {
  constexpr int GSZ = 64 / EPW;
  constexpr unsigned RB = (unsigned)RU4 * 16u;   // row bytes (3072 / 2048)
  int grp = (EPW == 2) ? (lane >> 5) : (lane >> 4);
  int lg = lane & (GSZ - 1);
  int lgc = (lg < ACT) ? lg : 0;       // pad lanes duplicate lane 0's line (coalesced, free)
  unsigned laneByte = (unsigned)(slice * ACT + lgc) * 16u;
  const char* __restrict__ inB = (const char*)in;
  int jb = __builtin_amdgcn_readfirstlane(rp[row]);
  int je = __builtin_amdgcn_readfirstlane(rp[row + 1]);
  int len = je - jb;

  f32x2 a0 = {0.f, 0.f}, a1 = {0.f, 0.f}, a2 = {0.f, 0.f}, a3 = {0.f, 0.f};

  constexpr int STEP = 4 * EPW;        // 4 gather instrs in flight per wave
  int i = jb;
  int eM = jb + (len / STEP) * STEP;
  for (; i < eM; i += STEP) {
    #pragma unroll
    for (int k = 0; k < 4; ++k) {
      unsigned int col; float w;
      {
        uint2 e0 = cw[i + k * EPW + 0];
        uint2 e1 = cw[i + k * EPW + 1];
        col = (grp & 1) ? e1.x : e0.x;
        w = __uint_as_float((grp & 1) ? e1.y : e0.y);
        if (EPW == 4) {
          uint2 e2 = cw[i + k * EPW + 2];
          uint2 e3 = cw[i + k * EPW + 3];
          unsigned int colB = (grp & 1) ? e3.x : e2.x;
          float wB = __uint_as_float((grp & 1) ? e3.y : e2.y);
          col = (grp & 2) ? colB : col;
          w = (grp & 2) ? wB : w;
        }
      }
      unsigned off = __umul24(col, RB) + laneByte;     // u32, < 31 MB: safe
      uint4v q = *(const uint4v*)(inB + off);
      f32x2 wv = {w, w};
      f32x2 v0 = {bflo(q.x), bfhi(q.x)};
      f32x2 v1 = {bflo(q.y), bfhi(q.y)};
      f32x2 v2 = {bflo(q.z), bfhi(q.z)};
      f32x2 v3 = {bflo(q.w), bfhi(q.w)};
      a0 += wv * v0; a1 += wv * v1; a2 += wv * v2; a3 += wv * v3;
    }
  }
  // masked tail, EPW edges per step (clamped uniform descriptor indices)
  for (; i < je; i += EPW) {
    unsigned int col; float w;
    {
      uint2 e0 = cw[i + 0];
      uint2 e1 = cw[(i + 1 < je) ? i + 1 : i];
      col = (grp & 1) ? e1.x : e0.x;
      w = __uint_as_float((grp & 1) ? e1.y : e0.y);
      if (EPW == 4) {
        uint2 e2 = cw[(i + 2 < je) ? i + 2 : i];
        uint2 e3 = cw[(i + 3 < je) ? i + 3 : i];
        unsigned int colB = (grp & 1) ? e3.x : e2.x;
        float wB = __uint_as_float((grp & 1) ? e3.y : e2.y);
        col = (grp & 2) ? colB : col;
        w = (grp & 2) ? wB : w;
      }
    }
    if (i + grp >= je) w = 0.f;        // invalid lanes contribute 0 (clamped addr is safe)
    unsigned off = __umul24(col, RB) + laneByte;
    uint4v q = *(const uint4v*)(inB + off);
    f32x2 wv = {w, w};
    f32x2 v0 = {bflo(q.x), bfhi(q.x)};
    f32x2 v1 = {bflo(q.y), bfhi(q.y)};
    f32x2 v2 = {bflo(q.z), bfhi(q.z)};
    f32x2 v3 = {bflo(q.w), bfhi(q.w)};
    a0 += wv * v0; a1 += wv * v1; a2 += wv * v2; a3 += wv * v3;
  }

  // cross-group reduce (idle-lane pairs stay among idle lanes; discarded)
  #pragma unroll
  for (int k = 0; k < 2; ++k) {
    float* pa = (k == 0) ? (float*)&a0 : (float*)&a2;
    // handled below component-wise
  }
  {
    float* aa = (float*)&a0;   // a0,a1,a2,a3 are consecutive? not guaranteed; do explicitly
  }
  if (EPW == 4) {
    a0.x += __shfl_xor(a0.x, 16); a0.y += __shfl_xor(a0.y, 16);
    a1.x += __shfl_xor(a1.x, 16); a1.y += __shfl_xor(a1.y, 16);
    a2.x += __shfl_xor(a2.x, 16); a2.y += __shfl_xor(a2.y, 16);
    a3.x += __shfl_xor(a3.x, 16); a3.y += __shfl_xor(a3.y, 16);
  }
  a0.x += __shfl_xor(a0.x, 32); a0.y += __shfl_xor(a0.y, 32);
  a1.x += __shfl_xor(a1.x, 32); a1.y += __shfl_xor(a1.y, 32);
  a2.x += __shfl_xor(a2.x, 32); a2.y += __shfl_xor(a2.y, 32);
  a3.x += __shfl_xor(a3.x, 32); a3.y += __shfl_xor(a3.y, 32);

  if (grp == 0 && lg < ACT) {
    uint4v o;
    o.x = pack2(alpha * a0.x, alpha * a0.y);
    o.y = pack2(alpha * a1.x, alpha * a1.y);
    o.z = pack2(alpha * a2.x, alpha * a2.y);
    o.w = pack2(alpha * a3.x, alpha * a3.y);
    out[(size_t)row * RU4 + slice * ACT + lg] = o;
  }
}

template<int RU4, int ACT, int EPW>
__launch_bounds__(256)
__global__ void prop_dualX(const uint4v* __restrict__ in,
                           uint4v* __restrict__ outF, uint4v* __restrict__ outB,
                           const int* __restrict__ rp_f, const uint2* __restrict__ cwf,
                           const int* __restrict__ rp_b, const uint2* __restrict__ cwb) {
  int lane = threadIdx.x & 63;
  int wave = threadIdx.x >> 6;
  int slice = blockIdx.x & 7;
  int row = ((blockIdx.x >> 3) << 2) + wave;
  prop_rowX<RU4, ACT, EPW>(in, outF, rp_f, cwf, row, slice, lane, 1.f);
  prop_rowX<RU4, ACT, EPW>(in, outB, rp_b, cwb, row, slice, lane, 1.f);
}

template<int RU4, int ACT, int EPW>
__launch_bounds__(256)
__global__ void prop_ckX(const uint4v* __restrict__ in, uint4v* __restrict__ out,
                         const int* __restrict__ rp, const uint2* __restrict__ cw,
                         float alpha) {
  int lane = threadIdx.x & 63;
  int wave = threadIdx.x >> 6;
  int slice = blockIdx.x & 7;
  int row = ((blockIdx.x >> 3) << 2) + wave;
  prop_rowX<RU4, ACT, EPW>(in, out, rp, cw, row, slice, lane, alpha);
}

// ---------------- MFMA multi-term GEMM ----------------
// C[128 x NT] per block; 4 waves, each 32 x NT. K = nterms*96.
// Weight columns for loop term t are taken at (t0 + t)*96.
// MFMA layouts (verified): A[m=lane&15][k=quad*8+j]; B[k=quad*8+j][n=lane&15];
//                          C/D col=lane&15, row=quad*4+reg.
// MODE 0: conv1 epilogue: v=sigmoid(bias+acc); col<64 -> rh0=v*h (bf16); else U=v (bf16)
// MODE 1: outp = bias + acc (f32, batch-major)
// MODE 2: cp = outp + acc; c=tanh(tanh(cp)); u from U_in; outp = u*h + (1-u)*c
struct Msrc {
  const uint4* xs[5];
  const uint4* rh[5];
};

template<int NT, int MODE>
__launch_bounds__(256)
__global__ void gemm_mfma(Msrc g, int nterms, int t0,
                          const unsigned short* __restrict__ Wt,
                          const float* __restrict__ bias,
                          float* __restrict__ outp,
                          unsigned short* __restrict__ rh0_s,
                          unsigned short* __restrict__ U_out,
                          const unsigned short* __restrict__ U_in,
                          const float* __restrict__ hglob) {
  constexpr int NJ = NT / 16;
  __shared__ __align__(16) unsigned short As[128][104];   // 13 x 16B per row (odd -> conflict-free)
  __shared__ __align__(16) unsigned short Bs[NT][104];

  int m0 = blockIdx.x * 128;
  int tid = threadIdx.x;
  int wave = tid >> 6;
  int lane = tid & 63;
  int quad = lane >> 4;
  int lm = lane & 15;
  int wm = wave * 32;
  int nodeBase = m0 >> 4;

  f32x4 acc[2][NJ];
  #pragma unroll
  for (int i = 0; i < 2; ++i)
    #pragma unroll
    for (int j = 0; j < NJ; ++j) acc[i][j] = (f32x4){0.f, 0.f, 0.f, 0.f};

  for (int t = 0; t < nterms; ++t) {
    const uint4* xs4 = g.xs[t];
    const uint4* rh4 = g.rh[t];
    if (rh4 == nullptr) {
      const uint4* src = xs4 + (size_t)m0 * 12;
      #pragma unroll
      for (int it = 0; it < 6; ++it) {
        int q = tid + it * 256;
        uint4 v = src[q];
        int row = q / 12, slot = q % 12;
        *(uint4*)&As[row][slot * 8] = v;
      }
    } else {
      #pragma unroll
      for (int it = 0; it < 6; ++it) {
        int q = tid + it * 256;
        int row = q / 12, slot = q % 12;
        int node = nodeBase + (row >> 4);
        int b = row & 15;
        uint4 v; int ci0;
        if (slot < 4) { v = xs4[(size_t)node * 192 + b * 12 + slot]; ci0 = slot * 8; }
        else          { v = rh4[(size_t)node * 128 + b * 8 + (slot - 4)]; ci0 = 32 + (slot - 4) * 8; }
        *(uint4*)&As[row][ci0] = v;
      }
    }
    for (int q = tid; q < NT * 12; q += 256) {
      int n = q / 12, slot = q % 12;
      uint4 v = *(const uint4*)(Wt + (size_t)n * 480 + (t0 + t) * 96 + slot * 8);
      *(uint4*)&Bs[n][slot * 8] = v;
    }
    __syncthreads();

    #pragma unroll
    for (int k32 = 0; k32 < 3; ++k32) {
      int kb = k32 * 32 + quad * 8;
      short8 a0 = *(const short8*)&As[wm + lm][kb];
      short8 a1 = *(const short8*)&As[wm + 16 + lm][kb];
      #pragma unroll
      for (int j = 0; j < NJ; ++j) {
        short8 bf = *(const short8*)&Bs[j * 16 + lm][kb];
        acc[0][j] = __builtin_amdgcn_mfma_f32_16x16x32_bf16(a0, bf, acc[0][j], 0, 0, 0);
        acc[1][j] = __builtin_amdgcn_mfma_f32_16x16x32_bf16(a1, bf, acc[1][j], 0, 0, 0);
      }
    }
    __syncthreads();
  }

  #pragma unroll
  for (int i = 0; i < 2; ++i) {
    #pragma unroll
    for (int j = 0; j < NJ; ++j) {
      int col = j * 16 + lm;
      #pragma unroll
      for (int r = 0; r < 4; ++r) {
        int row = m0 + wm + i * 16 + quad * 4 + r;
        int node = row >> 4, b = row & 15;
        float v = acc[i][j][r];
        if (MODE == 0) {
          float s = 1.f / (1.f + expf(-(bias[col] + v)));
          if (col < COUTn) {
            float hv = hglob[((size_t)b * Nn + node) * COUTn + col];
            rh0_s[(size_t)row * 64 + col] = (unsigned short)f2bfbits(s * hv);
          } else {
            U_out[(size_t)row * 64 + (col - COUTn)] = (unsigned short)f2bfbits(s);
          }
        } else if (MODE == 1) {
          outp[((size_t)b * Nn + node) * COUTn + col] = bias[col] + v;
        } else {
          size_t oa = ((size_t)b * Nn + node) * COUTn + col;
          float cp = outp[oa] + v;
          float c = tanhf(tanhf(cp));
          float u = bf2f(U_in[(size_t)row * 64 + col]);
          outp[oa] = u * hglob[oa] + (1.f - u) * c;
        }
      }
    }
  }
}

// ---------------- host ----------------
extern "C" void kernel_launch(void* const* d_in, const int* in_sizes, int n_in,
                              void* d_out, int out_size, void* d_ws, size_t ws_size,
                              hipStream_t stream) {
  const float* x   = (const float*)d_in[0];
  const float* h   = (const float*)d_in[1];
  const int*   idx = (const int*)d_in[2];
  const float* ew  = (const float*)d_in[3];
  const float* ru_param = (const float*)d_in[4];
  const float* ru_bias  = (const float*)d_in[5];
  const float* c_param  = (const float*)d_in[6];
  const float* c_bias   = (const float*)d_in[7];
  float* outp = (float*)d_out;
  (void)in_sizes; (void)n_in; (void)out_size; (void)ws_size;

  char* ws = (char*)d_ws;
  size_t off = 0;
  auto alloc = [&](size_t bytes) -> char* {
    char* p = ws + off;
    off += (bytes + 255) & ~(size_t)255;
    return p;
  };

  float* deg_f = (float*)alloc(40960);
  float* deg_b = (float*)alloc(40960);
  int*   cnt_f = (int*)alloc(40960);
  int*   cnt_b = (int*)alloc(40960);
  int*   rp_f  = (int*)alloc((Nn + 1) * sizeof(int));
  int*   rp_b  = (int*)alloc((Nn + 1) * sizeof(int));
  int*   cur_f = (int*)alloc(Nn * sizeof(int));
  int*   cur_b = (int*)alloc(Nn * sizeof(int));
  int*   flag  = (int*)alloc(256);
  uint2* cwf   = (uint2*)alloc((size_t)En * 8);
  uint2* cwb   = (uint2*)alloc((size_t)En * 8);
  unsigned short* Wt1 = (unsigned short*)alloc(128 * 480 * 2);
  unsigned short* Wt2 = (unsigned short*)alloc(64 * 480 * 2);

  unsigned int* A0   = (unsigned int*)alloc((size_t)Nn * WROWU * 4);
  unsigned int* T1f  = (unsigned int*)alloc((size_t)Nn * WROWU * 4);
  unsigned int* T1b  = (unsigned int*)alloc((size_t)Nn * WROWU * 4);
  unsigned int* T2f  = (unsigned int*)alloc((size_t)Nn * WROWU * 4);
  unsigned int* T2b  = (unsigned int*)alloc((size_t)Nn * WROWU * 4);
  unsigned int* rh0  = (unsigned int*)alloc((size_t)Nn * RHU * 4);
  unsigned int* rh1f = (unsigned int*)alloc((size_t)Nn * RHU * 4);
  unsigned int* rh1b = (unsigned int*)alloc((size_t)Nn * RHU * 4);
  unsigned int* Ubuf = (unsigned int*)alloc((size_t)Nn * RHU * 4);
  // ~241 MB total

  hipMemsetAsync(ws, 0, 4 * 40960, stream);
  detect_idx<<<1, 64, 0, stream>>>(idx, flag);
  deg_cnt_kernel<<<En / 256, 256, 0, stream>>>(idx, ew, deg_f, deg_b, cnt_f, cnt_b, flag);
  exscan_two<<<2, 256, 0, stream>>>(cnt_f, cnt_b, rp_f, rp_b, cur_f, cur_b, Nn);
  fill_csr<<<En / 256, 256, 0, stream>>>(idx, ew, deg_f, deg_b, cur_f, cur_b,
                                         cwf, cwb, flag);
  build_wt<<<240, 256, 0, stream>>>(ru_param, c_param, Wt1, Wt2);

  const int gBuild = Nn * WROWU / 256;
  const int gP = (Nn / 4) * 8;   // 4 rows/block (1 per wave) x 8 XCD slices

  // ===== conv1 diffusion (rows of 192 uint4, slices of 24 uint4, 2 edges/gather) =====
  build_x0_ru<<<gBuild, 256, 0, stream>>>(x, h, A0);
  prop_dualX<192, 24, 2><<<gP, 256, 0, stream>>>(
      (const uint4v*)A0, (uint4v*)T1f, (uint4v*)T1b, rp_f, cwf, rp_b, cwb);
  prop_ckX<192, 24, 2><<<gP, 256, 0, stream>>>(
      (const uint4v*)T1f, (uint4v*)T2f, rp_f, cwf, 2.f);
  prop_ckX<192, 24, 2><<<gP, 256, 0, stream>>>(
      (const uint4v*)T1b, (uint4v*)T2b, rp_b, cwb, 2.f);

  // ===== conv1 projection: one MFMA GEMM K=480, fused sigmoid + r*h + u-store =====
  Msrc g1;
  g1.xs[0] = (const uint4*)A0;  g1.rh[0] = nullptr;
  g1.xs[1] = (const uint4*)T1f; g1.rh[1] = nullptr;
  g1.xs[2] = (const uint4*)T1b; g1.rh[2] = nullptr;
  g1.xs[3] = (const uint4*)T2f; g1.rh[3] = nullptr;
  g1.xs[4] = (const uint4*)T2b; g1.rh[4] = nullptr;
  gemm_mfma<128, 0><<<MROWS / 128, 256, 0, stream>>>(
      g1, 5, 0, Wt1, ru_bias, nullptr,
      (unsigned short*)rh0, (unsigned short*)Ubuf, nullptr, h);

  // ===== conv2 diffusion on rh (rows of 128 uint4, slices of 16 uint4, 4 edges/gather) =====
  prop_dualX<128, 16, 4><<<gP, 256, 0, stream>>>(
      (const uint4v*)rh0, (uint4v*)rh1f, (uint4v*)rh1b, rp_f, cwf, rp_b, cwb);

  // conv2 pass A: terms 0,1,2 (weight base t0=0)
  Msrc g2a;
  g2a.xs[0] = (const uint4*)A0;  g2a.rh[0] = (const uint4*)rh0;
  g2a.xs[1] = (const uint4*)T1f; g2a.rh[1] = (const uint4*)rh1f;
  g2a.xs[2] = (const uint4*)T1b; g2a.rh[2] = (const uint4*)rh1b;
  g2a.xs[3] = nullptr; g2a.rh[3] = nullptr;
  g2a.xs[4] = nullptr; g2a.rh[4] = nullptr;
  gemm_mfma<64, 1><<<MROWS / 128, 256, 0, stream>>>(
      g2a, 3, 0, Wt2, c_bias, outp, nullptr, nullptr, nullptr, nullptr);

  // rh second-order terms (reuse rh0/rh1f storage after pass A consumed them)
  prop_ckX<128, 16, 4><<<gP, 256, 0, stream>>>(
      (const uint4v*)rh1f, (uint4v*)rh0, rp_f, cwf, 2.f);   // rh2f
  prop_ckX<128, 16, 4><<<gP, 256, 0, stream>>>(
      (const uint4v*)rh1b, (uint4v*)rh1f, rp_b, cwb, 2.f);  // rh2b

  // conv2 pass B: terms 3,4 (weight base t0=3) + fused GRU final
  Msrc g2b;
  g2b.xs[0] = (const uint4*)T2f; g2b.rh[0] = (const uint4*)rh0;
  g2b.xs[1] = (const uint4*)T2b; g2b.rh[1] = (const uint4*)rh1f;
  g2b.xs[2] = nullptr; g2b.rh[2] = nullptr;
  g2b.xs[3] = nullptr; g2b.rh[3] = nullptr;
  g2b.xs[4] = nullptr; g2b.rh[4] = nullptr;
  gemm_mfma<64, 2><<<MROWS / 128, 256, 0, stream>>>(
      g2b, 2, 3, Wt2, c_bias, outp, nullptr, nullptr,
      (const unsigned short*)Ubuf, h);
}

// Round 9
// 852.039 us; speedup vs baseline: 1.8272x; 1.0829x over previous
//
#include <hip/hip_runtime.h>
#include <stdint.h>
#include <stddef.h>

#define Bn    16
#define Nn    10000
#define En    320000
#define CIN   32
#define COUTn 64
#define CCn   96
#define WROWU 768           // uints per full node row (16 batches * 96ch / 2)
#define RHU   512           // uints per rh-only node row (16 * 64 / 2)
#define MROWS 160000        // Nn * Bn
#define GX0   (Nn * WROWU / 256)   // 30000 blocks for x0 build

typedef __attribute__((ext_vector_type(8))) short short8;   // 8 bf16 = 4 VGPRs
typedef __attribute__((ext_vector_type(4))) float f32x4;
typedef __attribute__((ext_vector_type(2))) float f32x2;
typedef __attribute__((ext_vector_type(4))) unsigned int uint4v;

// ---------------- bf16 helpers ----------------
__device__ __forceinline__ float bflo(unsigned int p) { return __uint_as_float(p << 16); }
__device__ __forceinline__ float bfhi(unsigned int p) { return __uint_as_float(p & 0xffff0000u); }
__device__ __forceinline__ float bf2f(unsigned short u) { return __uint_as_float(((unsigned int)u) << 16); }
__device__ __forceinline__ unsigned int f2bfbits(float f) {
  unsigned int x = __float_as_uint(f);
  return (x + 0x7fffu + ((x >> 16) & 1u)) >> 16;
}
__device__ __forceinline__ unsigned int pack2(float lo, float hi) {
  return f2bfbits(lo) | (f2bfbits(hi) << 16);
}

// ---------------- edge_index dtype detection (parallel, 64 lanes) ----------------
__global__ void detect_idx(const int* __restrict__ idx, int* __restrict__ flag) {
  int t = threadIdx.x;                 // 64 threads
  int v = idx[1 + 2 * t];              // odd positions 1..127
  unsigned long long bal = __ballot(v != 0);
  if (t == 0) flag[0] = (bal == 0ULL) ? 1 : 0;
}

__device__ __forceinline__ int gidx(const int* __restrict__ p, int i, int is64) {
  return is64 ? p[2 * (long long)i] : p[i];
}

// ---------------- degree + CSR row counts ----------------
__global__ void deg_cnt_kernel(const int* __restrict__ idx, const float* __restrict__ w,
                               float* __restrict__ deg_f, float* __restrict__ deg_b,
                               int* __restrict__ cnt_f, int* __restrict__ cnt_b,
                               const int* __restrict__ flag) {
  int e = blockIdx.x * 256 + threadIdx.x;
  int is64 = flag[0];
  if (e < En) {
    int s = gidx(idx, e, is64);
    int d = gidx(idx, En + e, is64);
    float we = w[e];
    atomicAdd(&deg_f[s], we);
    atomicAdd(&deg_b[d], we);
    atomicAdd(&cnt_f[d], 1);
    atomicAdd(&cnt_b[s], 1);
  }
}

// ---------------- exclusive scan (thread-coarsened: 40 elems/thread) ----------------
__global__ void exscan_two(const int* __restrict__ cnt_f, const int* __restrict__ cnt_b,
                           int* __restrict__ rp_f, int* __restrict__ rp_b,
                           int* __restrict__ cur_f, int* __restrict__ cur_b, int n) {
  const int* cnt = (blockIdx.x == 0) ? cnt_f : cnt_b;
  int* rp  = (blockIdx.x == 0) ? rp_f  : rp_b;
  int* cur = (blockIdx.x == 0) ? cur_f : cur_b;
  __shared__ int sh[256];
  int t = threadIdx.x;
  int CH = (n + 255) / 256;
  int s0 = t * CH;
  int s1 = s0 + CH; if (s1 > n) s1 = n;
  int s = 0;
  for (int i = s0; i < s1; ++i) s += cnt[i];
  sh[t] = s;
  __syncthreads();
  for (int off = 1; off < 256; off <<= 1) {
    int x = (t >= off) ? sh[t - off] : 0;
    __syncthreads();
    sh[t] += x;
    __syncthreads();
  }
  int run = sh[t] - s;                 // exclusive prefix for this thread's chunk
  for (int i = s0; i < s1; ++i) {
    rp[i] = run; cur[i] = run; run += cnt[i];
  }
  if (t == 255) rp[n] = sh[255];
}

// ---------------- CSR fill: packed (col, w) uint2 ----------------
__global__ void fill_csr(const int* __restrict__ idx, const float* __restrict__ w,
                         const float* __restrict__ deg_f, const float* __restrict__ deg_b,
                         int* __restrict__ cur_f, int* __restrict__ cur_b,
                         uint2* __restrict__ cwf, uint2* __restrict__ cwb,
                         const int* __restrict__ flag) {
  int e = blockIdx.x * 256 + threadIdx.x;
  int is64 = flag[0];
  if (e < En) {
    int s = gidx(idx, e, is64);
    int d = gidx(idx, En + e, is64);
    float we = w[e];
    int pf = atomicAdd(&cur_f[d], 1);
    cwf[pf] = make_uint2((unsigned int)s, __float_as_uint(we / deg_f[s]));
    int pb = atomicAdd(&cur_b[s], 1);
    cwb[pb] = make_uint2((unsigned int)d, __float_as_uint(we / deg_b[d]));
  }
}

// ---------------- fused X0 builder + weight prep ----------------
// blocks [0, GX0): bf16 X0 rows; blocks [GX0, GX0+240): transposed bf16 weights
// with W0 folded (W0 - W3 - W4).
__global__ void build_x0_wt(const float* __restrict__ x, const float* __restrict__ h,
                            unsigned int* __restrict__ X0,
                            const float* __restrict__ ru_p, const float* __restrict__ c_p,
                            unsigned short* __restrict__ Wt1, unsigned short* __restrict__ Wt2) {
  if (blockIdx.x < GX0) {
    long long p = (long long)blockIdx.x * 256 + threadIdx.x;
    int node = (int)(p / WROWU);
    int rem = (int)(p % WROWU);
    int b = rem / 48;
    int ci = (rem % 48) * 2;
    float lo, hi;
    if (ci < CIN) {
      const float* s = x + ((size_t)b * Nn + node) * CIN + ci;
      lo = s[0]; hi = s[1];
    } else {
      const float* s = h + ((size_t)b * Nn + node) * COUTn + (ci - CIN);
      lo = s[0]; hi = s[1];
    }
    X0[p] = pack2(lo, hi);
  } else {
    int i = (blockIdx.x - GX0) * 256 + threadIdx.x;
    if (i < 128 * 480) {
      int n = i / 480, k = i % 480;
      int t = k / 96, kk = k % 96;
      float v;
      if (t == 0) v = ru_p[(kk * 5 + 0) * 128 + n] - ru_p[(kk * 5 + 3) * 128 + n] - ru_p[(kk * 5 + 4) * 128 + n];
      else        v = ru_p[(kk * 5 + t) * 128 + n];
      Wt1[i] = (unsigned short)f2bfbits(v);
    }
    if (i < 64 * 480) {
      int n = i / 480, k = i % 480;
      int t = k / 96, kk = k % 96;
      float v;
      if (t == 0) v = c_p[(kk * 5 + 0) * 64 + n] - c_p[(kk * 5 + 3) * 64 + n] - c_p[(kk * 5 + 4) * 64 + n];
      else        v = c_p[(kk * 5 + t) * 64 + n];
      Wt2[i] = (unsigned short)f2bfbits(v);
    }
  }
}

// ---------------- XCD-sliced propagation, multi-edge waves, scalar descriptors ----
// Node rows of RU4 uint4 are split into 8 channel slices of ACT uint4.
// slice = blockIdx & 7 -> each XCD gathers only its own 3.84/2.56 MB slice,
// L2-resident (verified FETCH 627->175 MB in R1).
// One row per wave; EPW edges per gather instruction (R7: -25% total).
// Edge descriptors at WAVE-UNIFORM indices (-> s_load scalar pipe; R3/R4/R5:
// per-lane/nontemporal descriptor loads force the vector path, up to -2x),
// then per-lane cndmask-selected by group id.
// R8: 32-bit umul24 addressing + packed f32 accumulation. (R8: -4%, now
// mixed VALU/TA/latency regime -> structure frozen.)
template<int RU4, int ACT, int EPW>
__device__ __forceinline__ void prop_rowX(const uint4v* __restrict__ in,
                                          uint4v* __restrict__ out,
                                          const int* __restrict__ rp,
                                          const uint2* __restrict__ cw,
                                          int row, int slice, int lane, float alpha) {
  constexpr int GSZ = 64 / EPW;
  constexpr unsigned RB = (unsigned)RU4 * 16u;   // row bytes (3072 / 2048)
  int grp = (EPW == 2) ? (lane >> 5) : (lane >> 4);
  int lg = lane & (GSZ - 1);
  int lgc = (lg < ACT) ? lg : 0;       // pad lanes duplicate lane 0's line (coalesced, free)
  unsigned laneByte = (unsigned)(slice * ACT + lgc) * 16u;
  const char* __restrict__ inB = (const char*)in;
  int jb = __builtin_amdgcn_readfirstlane(rp[row]);
  int je = __builtin_amdgcn_readfirstlane(rp[row + 1]);
  int len = je - jb;

  f32x2 a0 = {0.f, 0.f}, a1 = {0.f, 0.f}, a2 = {0.f, 0.f}, a3 = {0.f, 0.f};

  constexpr int STEP = 4 * EPW;        // 4 gather instrs in flight per wave
  int i = jb;
  int eM = jb + (len / STEP) * STEP;
  for (; i < eM; i += STEP) {
    #pragma unroll
    for (int k = 0; k < 4; ++k) {
      unsigned int col; float w;
      {
        uint2 e0 = cw[i + k * EPW + 0];
        uint2 e1 = cw[i + k * EPW + 1];
        col = (grp & 1) ? e1.x : e0.x;
        w = __uint_as_float((grp & 1) ? e1.y : e0.y);
        if (EPW == 4) {
          uint2 e2 = cw[i + k * EPW + 2];
          uint2 e3 = cw[i + k * EPW + 3];
          unsigned int colB = (grp & 1) ? e3.x : e2.x;
          float wB = __uint_as_float((grp & 1) ? e3.y : e2.y);
          col = (grp & 2) ? colB : col;
          w = (grp & 2) ? wB : w;
        }
      }
      unsigned off = __umul24(col, RB) + laneByte;     // u32, < 31 MB: safe
      uint4v q = *(const uint4v*)(inB + off);
      f32x2 wv = {w, w};
      f32x2 v0 = {bflo(q.x), bfhi(q.x)};
      f32x2 v1 = {bflo(q.y), bfhi(q.y)};
      f32x2 v2 = {bflo(q.z), bfhi(q.z)};
      f32x2 v3 = {bflo(q.w), bfhi(q.w)};
      a0 += wv * v0; a1 += wv * v1; a2 += wv * v2; a3 += wv * v3;
    }
  }
  // masked tail, EPW edges per step (clamped uniform descriptor indices)
  for (; i < je; i += EPW) {
    unsigned int col; float w;
    {
      uint2 e0 = cw[i + 0];
      uint2 e1 = cw[(i + 1 < je) ? i + 1 : i];
      col = (grp & 1) ? e1.x : e0.x;
      w = __uint_as_float((grp & 1) ? e1.y : e0.y);
      if (EPW == 4) {
        uint2 e2 = cw[(i + 2 < je) ? i + 2 : i];
        uint2 e3 = cw[(i + 3 < je) ? i + 3 : i];
        unsigned int colB = (grp & 1) ? e3.x : e2.x;
        float wB = __uint_as_float((grp & 1) ? e3.y : e2.y);
        col = (grp & 2) ? colB : col;
        w = (grp & 2) ? wB : w;
      }
    }
    if (i + grp >= je) w = 0.f;        // invalid lanes contribute 0 (clamped addr is safe)
    unsigned off = __umul24(col, RB) + laneByte;
    uint4v q = *(const uint4v*)(inB + off);
    f32x2 wv = {w, w};
    f32x2 v0 = {bflo(q.x), bfhi(q.x)};
    f32x2 v1 = {bflo(q.y), bfhi(q.y)};
    f32x2 v2 = {bflo(q.z), bfhi(q.z)};
    f32x2 v3 = {bflo(q.w), bfhi(q.w)};
    a0 += wv * v0; a1 += wv * v1; a2 += wv * v2; a3 += wv * v3;
  }

  // cross-group reduce
  if (EPW == 4) {
    a0.x += __shfl_xor(a0.x, 16); a0.y += __shfl_xor(a0.y, 16);
    a1.x += __shfl_xor(a1.x, 16); a1.y += __shfl_xor(a1.y, 16);
    a2.x += __shfl_xor(a2.x, 16); a2.y += __shfl_xor(a2.y, 16);
    a3.x += __shfl_xor(a3.x, 16); a3.y += __shfl_xor(a3.y, 16);
  }
  a0.x += __shfl_xor(a0.x, 32); a0.y += __shfl_xor(a0.y, 32);
  a1.x += __shfl_xor(a1.x, 32); a1.y += __shfl_xor(a1.y, 32);
  a2.x += __shfl_xor(a2.x, 32); a2.y += __shfl_xor(a2.y, 32);
  a3.x += __shfl_xor(a3.x, 32); a3.y += __shfl_xor(a3.y, 32);

  if (grp == 0 && lg < ACT) {
    uint4v o;
    o.x = pack2(alpha * a0.x, alpha * a0.y);
    o.y = pack2(alpha * a1.x, alpha * a1.y);
    o.z = pack2(alpha * a2.x, alpha * a2.y);
    o.w = pack2(alpha * a3.x, alpha * a3.y);
    out[(size_t)row * RU4 + slice * ACT + lg] = o;
  }
}

template<int RU4, int ACT, int EPW>
__launch_bounds__(256)
__global__ void prop_dualX(const uint4v* __restrict__ in,
                           uint4v* __restrict__ outF, uint4v* __restrict__ outB,
                           const int* __restrict__ rp_f, const uint2* __restrict__ cwf,
                           const int* __restrict__ rp_b, const uint2* __restrict__ cwb) {
  int lane = threadIdx.x & 63;
  int wave = threadIdx.x >> 6;
  int slice = blockIdx.x & 7;
  int row = ((blockIdx.x >> 3) << 2) + wave;
  prop_rowX<RU4, ACT, EPW>(in, outF, rp_f, cwf, row, slice, lane, 1.f);
  prop_rowX<RU4, ACT, EPW>(in, outB, rp_b, cwb, row, slice, lane, 1.f);
}

template<int RU4, int ACT, int EPW>
__launch_bounds__(256)
__global__ void prop_ckX(const uint4v* __restrict__ in, uint4v* __restrict__ out,
                         const int* __restrict__ rp, const uint2* __restrict__ cw,
                         float alpha) {
  int lane = threadIdx.x & 63;
  int wave = threadIdx.x >> 6;
  int slice = blockIdx.x & 7;
  int row = ((blockIdx.x >> 3) << 2) + wave;
  prop_rowX<RU4, ACT, EPW>(in, out, rp, cw, row, slice, lane, alpha);
}

// ---------------- MFMA multi-term GEMM ----------------
// C[128 x NT] per block; 4 waves, each 32 x NT. K = nterms*96.
// Weight columns for loop term t are taken at (t0 + t)*96.
// MFMA layouts (verified): A[m=lane&15][k=quad*8+j]; B[k=quad*8+j][n=lane&15];
//                          C/D col=lane&15, row=quad*4+reg.
// MODE 0: conv1 epilogue: v=sigmoid(bias+acc); col<64 -> rh0=v*h (bf16); else U=v (bf16)
// MODE 1: outp = bias + acc (f32, batch-major)
// MODE 2: cp = outp + acc; c=tanh(tanh(cp)); u from U_in; outp = u*h + (1-u)*c
struct Msrc {
  const uint4* xs[5];
  const uint4* rh[5];
};

template<int NT, int MODE>
__device__ __forceinline__ void gemm_body(int blk, Msrc g, int nterms, int t0,
                          const unsigned short* __restrict__ Wt,
                          const float* __restrict__ bias,
                          float* __restrict__ outp,
                          unsigned short* __restrict__ rh0_s,
                          unsigned short* __restrict__ U_out,
                          const unsigned short* __restrict__ U_in,
                          const float* __restrict__ hglob) {
  constexpr int NJ = NT / 16;
  __shared__ __align__(16) unsigned short As[128][104];   // 13 x 16B per row (odd -> conflict-free)
  __shared__ __align__(16) unsigned short Bs[NT][104];

  int m0 = blk * 128;
  int tid = threadIdx.x;
  int wave = tid >> 6;
  int lane = tid & 63;
  int quad = lane >> 4;
  int lm = lane & 15;
  int wm = wave * 32;
  int nodeBase = m0 >> 4;

  f32x4 acc[2][NJ];
  #pragma unroll
  for (int i = 0; i < 2; ++i)
    #pragma unroll
    for (int j = 0; j < NJ; ++j) acc[i][j] = (f32x4){0.f, 0.f, 0.f, 0.f};

  for (int t = 0; t < nterms; ++t) {
    const uint4* xs4 = g.xs[t];
    const uint4* rh4 = g.rh[t];
    if (rh4 == nullptr) {
      const uint4* src = xs4 + (size_t)m0 * 12;
      #pragma unroll
      for (int it = 0; it < 6; ++it) {
        int q = tid + it * 256;
        uint4 v = src[q];
        int row = q / 12, slot = q % 12;
        *(uint4*)&As[row][slot * 8] = v;
      }
    } else {
      #pragma unroll
      for (int it = 0; it < 6; ++it) {
        int q = tid + it * 256;
        int row = q / 12, slot = q % 12;
        int node = nodeBase + (row >> 4);
        int b = row & 15;
        uint4 v; int ci0;
        if (slot < 4) { v = xs4[(size_t)node * 192 + b * 12 + slot]; ci0 = slot * 8; }
        else          { v = rh4[(size_t)node * 128 + b * 8 + (slot - 4)]; ci0 = 32 + (slot - 4) * 8; }
        *(uint4*)&As[row][ci0] = v;
      }
    }
    for (int q = tid; q < NT * 12; q += 256) {
      int n = q / 12, slot = q % 12;
      uint4 v = *(const uint4*)(Wt + (size_t)n * 480 + (t0 + t) * 96 + slot * 8);
      *(uint4*)&Bs[n][slot * 8] = v;
    }
    __syncthreads();

    #pragma unroll
    for (int k32 = 0; k32 < 3; ++k32) {
      int kb = k32 * 32 + quad * 8;
      short8 a0 = *(const short8*)&As[wm + lm][kb];
      short8 a1 = *(const short8*)&As[wm + 16 + lm][kb];
      #pragma unroll
      for (int j = 0; j < NJ; ++j) {
        short8 bf = *(const short8*)&Bs[j * 16 + lm][kb];
        acc[0][j] = __builtin_amdgcn_mfma_f32_16x16x32_bf16(a0, bf, acc[0][j], 0, 0, 0);
        acc[1][j] = __builtin_amdgcn_mfma_f32_16x16x32_bf16(a1, bf, acc[1][j], 0, 0, 0);
      }
    }
    __syncthreads();
  }

  #pragma unroll
  for (int i = 0; i < 2; ++i) {
    #pragma unroll
    for (int j = 0; j < NJ; ++j) {
      int col = j * 16 + lm;
      #pragma unroll
      for (int r = 0; r < 4; ++r) {
        int row = m0 + wm + i * 16 + quad * 4 + r;
        int node = row >> 4, b = row & 15;
        float v = acc[i][j][r];
        if (MODE == 0) {
          float s = 1.f / (1.f + expf(-(bias[col] + v)));
          if (col < COUTn) {
            float hv = hglob[((size_t)b * Nn + node) * COUTn + col];
            rh0_s[(size_t)row * 64 + col] = (unsigned short)f2bfbits(s * hv);
          } else {
            U_out[(size_t)row * 64 + (col - COUTn)] = (unsigned short)f2bfbits(s);
          }
        } else if (MODE == 1) {
          outp[((size_t)b * Nn + node) * COUTn + col] = bias[col] + v;
        } else {
          size_t oa = ((size_t)b * Nn + node) * COUTn + col;
          float cp = outp[oa] + v;
          float c = tanhf(tanhf(cp));
          float u = bf2f(U_in[(size_t)row * 64 + col]);
          outp[oa] = u * hglob[oa] + (1.f - u) * c;
        }
      }
    }
  }
}

template<int NT, int MODE>
__launch_bounds__(256)
__global__ void gemm_mfma(Msrc g, int nterms, int t0,
                          const unsigned short* __restrict__ Wt,
                          const float* __restrict__ bias,
                          float* __restrict__ outp,
                          unsigned short* __restrict__ rh0_s,
                          unsigned short* __restrict__ U_out,
                          const unsigned short* __restrict__ U_in,
                          const float* __restrict__ hglob) {
  gemm_body<NT, MODE>(blockIdx.x, g, nterms, t0, Wt, bias, outp, rh0_s, U_out, U_in, hglob);
}

// ---------------- fused: gemm2a (MODE 1) overlapped with conv2 ck F/B ----------------
// Regions: [0,1256) gemm (1250 active; gemm blocks start first = long-running),
// [1256, 21256) ck-F, [21256, 41256) ck-B. All bases %8==0 so slice=b2&7 stays
// XCD-consistent. Hazard-free: cks write NEW rh2 buffers (not rh0/rh1f that the
// gemm reads concurrently).
__launch_bounds__(256)
__global__ void fused_g2a(Msrc g,
                          const unsigned short* __restrict__ Wt,
                          const float* __restrict__ bias,
                          float* __restrict__ outp,
                          const uint4v* __restrict__ inF, uint4v* __restrict__ outF,
                          const int* __restrict__ rp_f, const uint2* __restrict__ cwf,
                          const uint4v* __restrict__ inB, uint4v* __restrict__ outB,
                          const int* __restrict__ rp_b, const uint2* __restrict__ cwb) {
  int b = blockIdx.x;
  if (b < 1256) {
    if (b < 1250)
      gemm_body<64, 1>(b, g, 3, 0, Wt, bias, outp, nullptr, nullptr, nullptr, nullptr);
    return;
  }
  int lane = threadIdx.x & 63;
  int wave = threadIdx.x >> 6;
  if (b < 21256) {
    int b2 = b - 1256;
    prop_rowX<128, 16, 4>(inF, outF, rp_f, cwf, ((b2 >> 3) << 2) + wave, b2 & 7, lane, 2.f);
  } else {
    int b2 = b - 21256;
    prop_rowX<128, 16, 4>(inB, outB, rp_b, cwb, ((b2 >> 3) << 2) + wave, b2 & 7, lane, 2.f);
  }
}

// ---------------- host ----------------
extern "C" void kernel_launch(void* const* d_in, const int* in_sizes, int n_in,
                              void* d_out, int out_size, void* d_ws, size_t ws_size,
                              hipStream_t stream) {
  const float* x   = (const float*)d_in[0];
  const float* h   = (const float*)d_in[1];
  const int*   idx = (const int*)d_in[2];
  const float* ew  = (const float*)d_in[3];
  const float* ru_param = (const float*)d_in[4];
  const float* ru_bias  = (const float*)d_in[5];
  const float* c_param  = (const float*)d_in[6];
  const float* c_bias   = (const float*)d_in[7];
  float* outp = (float*)d_out;
  (void)in_sizes; (void)n_in; (void)out_size;

  char* ws = (char*)d_ws;
  size_t off = 0;
  auto alloc = [&](size_t bytes) -> char* {
    char* p = ws + off;
    off += (bytes + 255) & ~(size_t)255;
    return p;
  };

  float* deg_f = (float*)alloc(40960);
  float* deg_b = (float*)alloc(40960);
  int*   cnt_f = (int*)alloc(40960);
  int*   cnt_b = (int*)alloc(40960);
  int*   rp_f  = (int*)alloc((Nn + 1) * sizeof(int));
  int*   rp_b  = (int*)alloc((Nn + 1) * sizeof(int));
  int*   cur_f = (int*)alloc(Nn * sizeof(int));
  int*   cur_b = (int*)alloc(Nn * sizeof(int));
  int*   flag  = (int*)alloc(256);
  uint2* cwf   = (uint2*)alloc((size_t)En * 8);
  uint2* cwb   = (uint2*)alloc((size_t)En * 8);
  unsigned short* Wt1 = (unsigned short*)alloc(128 * 480 * 2);
  unsigned short* Wt2 = (unsigned short*)alloc(64 * 480 * 2);

  unsigned int* A0   = (unsigned int*)alloc((size_t)Nn * WROWU * 4);
  unsigned int* T1f  = (unsigned int*)alloc((size_t)Nn * WROWU * 4);
  unsigned int* T1b  = (unsigned int*)alloc((size_t)Nn * WROWU * 4);
  unsigned int* T2f  = (unsigned int*)alloc((size_t)Nn * WROWU * 4);
  unsigned int* T2b  = (unsigned int*)alloc((size_t)Nn * WROWU * 4);
  unsigned int* rh0  = (unsigned int*)alloc((size_t)Nn * RHU * 4);
  unsigned int* rh1f = (unsigned int*)alloc((size_t)Nn * RHU * 4);
  unsigned int* rh1b = (unsigned int*)alloc((size_t)Nn * RHU * 4);
  unsigned int* Ubuf = (unsigned int*)alloc((size_t)Nn * RHU * 4);
  // extra buffers for the fused (overlapped) conv2 second-order pass
  unsigned int* rh2fN = (unsigned int*)alloc((size_t)Nn * RHU * 4);
  unsigned int* rh2bN = (unsigned int*)alloc((size_t)Nn * RHU * 4);
  bool bigws = (off <= ws_size);       // fall back to sequential if ws too small

  hipMemsetAsync(ws, 0, 4 * 40960, stream);
  detect_idx<<<1, 64, 0, stream>>>(idx, flag);
  deg_cnt_kernel<<<En / 256, 256, 0, stream>>>(idx, ew, deg_f, deg_b, cnt_f, cnt_b, flag);
  exscan_two<<<2, 256, 0, stream>>>(cnt_f, cnt_b, rp_f, rp_b, cur_f, cur_b, Nn);
  fill_csr<<<En / 256, 256, 0, stream>>>(idx, ew, deg_f, deg_b, cur_f, cur_b,
                                         cwf, cwb, flag);
  build_x0_wt<<<GX0 + 240, 256, 0, stream>>>(x, h, A0, ru_param, c_param, Wt1, Wt2);

  const int gP = (Nn / 4) * 8;   // 4 rows/block (1 per wave) x 8 XCD slices

  // ===== conv1 diffusion (rows of 192 uint4, slices of 24 uint4, 2 edges/gather) =====
  prop_dualX<192, 24, 2><<<gP, 256, 0, stream>>>(
      (const uint4v*)A0, (uint4v*)T1f, (uint4v*)T1b, rp_f, cwf, rp_b, cwb);
  prop_ckX<192, 24, 2><<<gP, 256, 0, stream>>>(
      (const uint4v*)T1f, (uint4v*)T2f, rp_f, cwf, 2.f);
  prop_ckX<192, 24, 2><<<gP, 256, 0, stream>>>(
      (const uint4v*)T1b, (uint4v*)T2b, rp_b, cwb, 2.f);

  // ===== conv1 projection: one MFMA GEMM K=480, fused sigmoid + r*h + u-store =====
  Msrc g1;
  g1.xs[0] = (const uint4*)A0;  g1.rh[0] = nullptr;
  g1.xs[1] = (const uint4*)T1f; g1.rh[1] = nullptr;
  g1.xs[2] = (const uint4*)T1b; g1.rh[2] = nullptr;
  g1.xs[3] = (const uint4*)T2f; g1.rh[3] = nullptr;
  g1.xs[4] = (const uint4*)T2b; g1.rh[4] = nullptr;
  gemm_mfma<128, 0><<<MROWS / 128, 256, 0, stream>>>(
      g1, 5, 0, Wt1, ru_bias, nullptr,
      (unsigned short*)rh0, (unsigned short*)Ubuf, nullptr, h);

  // ===== conv2 diffusion on rh (rows of 128 uint4, slices of 16 uint4, 4 edges/gather) =====
  prop_dualX<128, 16, 4><<<gP, 256, 0, stream>>>(
      (const uint4v*)rh0, (uint4v*)rh1f, (uint4v*)rh1b, rp_f, cwf, rp_b, cwb);

  // conv2 pass A (terms 0,1,2) overlapped with the rh second-order propagations
  Msrc g2a;
  g2a.xs[0] = (const uint4*)A0;  g2a.rh[0] = (const uint4*)rh0;
  g2a.xs[1] = (const uint4*)T1f; g2a.rh[1] = (const uint4*)rh1f;
  g2a.xs[2] = (const uint4*)T1b; g2a.rh[2] = (const uint4*)rh1b;
  g2a.xs[3] = nullptr; g2a.rh[3] = nullptr;
  g2a.xs[4] = nullptr; g2a.rh[4] = nullptr;

  const uint4* g2b_rh0;
  const uint4* g2b_rh1;
  if (bigws) {
    fused_g2a<<<41256, 256, 0, stream>>>(
        g2a, Wt2, c_bias, outp,
        (const uint4v*)rh1f, (uint4v*)rh2fN, rp_f, cwf,
        (const uint4v*)rh1b, (uint4v*)rh2bN, rp_b, cwb);
    g2b_rh0 = (const uint4*)rh2fN;
    g2b_rh1 = (const uint4*)rh2bN;
  } else {
    gemm_mfma<64, 1><<<MROWS / 128, 256, 0, stream>>>(
        g2a, 3, 0, Wt2, c_bias, outp, nullptr, nullptr, nullptr, nullptr);
    prop_ckX<128, 16, 4><<<gP, 256, 0, stream>>>(
        (const uint4v*)rh1f, (uint4v*)rh0, rp_f, cwf, 2.f);   // rh2f -> rh0
    prop_ckX<128, 16, 4><<<gP, 256, 0, stream>>>(
        (const uint4v*)rh1b, (uint4v*)rh1f, rp_b, cwb, 2.f);  // rh2b -> rh1f
    g2b_rh0 = (const uint4*)rh0;
    g2b_rh1 = (const uint4*)rh1f;
  }

  // conv2 pass B: terms 3,4 (weight base t0=3) + fused GRU final
  Msrc g2b;
  g2b.xs[0] = (const uint4*)T2f; g2b.rh[0] = g2b_rh0;
  g2b.xs[1] = (const uint4*)T2b; g2b.rh[1] = g2b_rh1;
  g2b.xs[2] = nullptr; g2b.rh[2] = nullptr;
  g2b.xs[3] = nullptr; g2b.rh[3] = nullptr;
  g2b.xs[4] = nullptr; g2b.rh[4] = nullptr;
  gemm_mfma<64, 2><<<MROWS / 128, 256, 0, stream>>>(
      g2b, 2, 3, Wt2, c_bias, outp, nullptr, nullptr,
      (const unsigned short*)Ubuf, h);
}

// Round 10
// 811.520 us; speedup vs baseline: 1.9184x; 1.0499x over previous
//
#include <hip/hip_runtime.h>
#include <stdint.h>
#include <stddef.h>

#define Bn    16
#define Nn    10000
#define En    320000
#define CIN   32
#define COUTn 64
#define CCn   96
#define WROWU 768           // uints per full node row (16 batches * 96ch / 2)
#define RHU   512           // uints per rh-only node row (16 * 64 / 2)
#define MROWS 160000        // Nn * Bn
#define GDEG  (En / 256)           // 1250 degree blocks
#define GX0   (Nn * WROWU / 256)   // 30000 blocks for x0 build

typedef __attribute__((ext_vector_type(8))) short short8;   // 8 bf16 = 4 VGPRs
typedef __attribute__((ext_vector_type(4))) float f32x4;
typedef __attribute__((ext_vector_type(2))) float f32x2;
typedef __attribute__((ext_vector_type(4))) unsigned int uint4v;

// ---------------- direct global->LDS (gfx950) ----------------
#if __has_builtin(__builtin_amdgcn_global_load_lds)
#define HAVE_GLL 1
typedef __attribute__((address_space(3))) unsigned char lds_u8;
typedef __attribute__((address_space(1))) const unsigned char glb_u8;
// HW semantics: LDS dest = wave-uniform base + lane*16; global src is per-lane.
__device__ __forceinline__ void gll16(const void* g, void* l) {
  __builtin_amdgcn_global_load_lds((glb_u8*)g, (lds_u8*)l, 16, 0, 0);
}
#else
#define HAVE_GLL 0
#endif

// ---------------- bf16 helpers ----------------
__device__ __forceinline__ float bflo(unsigned int p) { return __uint_as_float(p << 16); }
__device__ __forceinline__ float bfhi(unsigned int p) { return __uint_as_float(p & 0xffff0000u); }
__device__ __forceinline__ float bf2f(unsigned short u) { return __uint_as_float(((unsigned int)u) << 16); }
__device__ __forceinline__ unsigned int f2bfbits(float f) {
  unsigned int x = __float_as_uint(f);
  return (x + 0x7fffu + ((x >> 16) & 1u)) >> 16;
}
__device__ __forceinline__ unsigned int pack2(float lo, float hi) {
  return f2bfbits(lo) | (f2bfbits(hi) << 16);
}

// ---------------- edge_index dtype detection (parallel, 64 lanes) ----------------
__global__ void detect_idx(const int* __restrict__ idx, int* __restrict__ flag) {
  int t = threadIdx.x;                 // 64 threads
  int v = idx[1 + 2 * t];              // odd positions 1..127
  unsigned long long bal = __ballot(v != 0);
  if (t == 0) flag[0] = (bal == 0ULL) ? 1 : 0;
}

__device__ __forceinline__ int gidx(const int* __restrict__ p, int i, int is64) {
  return is64 ? p[2 * (long long)i] : p[i];
}

// ---------------- fused: degree/CSR counts + X0 build + weight prep ----------------
// These are mutually independent; region-split one dispatch hides the x0 build
// under the degree pass. blocks [0,GDEG): degrees; [GDEG,GDEG+GX0): X0 rows;
// [GDEG+GX0, +240): transposed bf16 weights with W0 folded (W0 - W3 - W4).
__global__ void deg_x0_wt(const int* __restrict__ idx, const float* __restrict__ w,
                          float* __restrict__ deg_f, float* __restrict__ deg_b,
                          int* __restrict__ cnt_f, int* __restrict__ cnt_b,
                          const int* __restrict__ flag,
                          const float* __restrict__ x, const float* __restrict__ h,
                          unsigned int* __restrict__ X0,
                          const float* __restrict__ ru_p, const float* __restrict__ c_p,
                          unsigned short* __restrict__ Wt1, unsigned short* __restrict__ Wt2) {
  int blk = blockIdx.x;
  if (blk < GDEG) {
    int e = blk * 256 + threadIdx.x;
    int is64 = flag[0];
    if (e < En) {
      int s = gidx(idx, e, is64);
      int d = gidx(idx, En + e, is64);
      float we = w[e];
      atomicAdd(&deg_f[s], we);
      atomicAdd(&deg_b[d], we);
      atomicAdd(&cnt_f[d], 1);
      atomicAdd(&cnt_b[s], 1);
    }
  } else if (blk < GDEG + GX0) {
    long long p = (long long)(blk - GDEG) * 256 + threadIdx.x;
    int node = (int)(p / WROWU);
    int rem = (int)(p % WROWU);
    int b = rem / 48;
    int ci = (rem % 48) * 2;
    float lo, hi;
    if (ci < CIN) {
      const float* s = x + ((size_t)b * Nn + node) * CIN + ci;
      lo = s[0]; hi = s[1];
    } else {
      const float* s = h + ((size_t)b * Nn + node) * COUTn + (ci - CIN);
      lo = s[0]; hi = s[1];
    }
    X0[p] = pack2(lo, hi);
  } else {
    int i = (blk - GDEG - GX0) * 256 + threadIdx.x;
    if (i < 128 * 480) {
      int n = i / 480, k = i % 480;
      int t = k / 96, kk = k % 96;
      float v;
      if (t == 0) v = ru_p[(kk * 5 + 0) * 128 + n] - ru_p[(kk * 5 + 3) * 128 + n] - ru_p[(kk * 5 + 4) * 128 + n];
      else        v = ru_p[(kk * 5 + t) * 128 + n];
      Wt1[i] = (unsigned short)f2bfbits(v);
    }
    if (i < 64 * 480) {
      int n = i / 480, k = i % 480;
      int t = k / 96, kk = k % 96;
      float v;
      if (t == 0) v = c_p[(kk * 5 + 0) * 64 + n] - c_p[(kk * 5 + 3) * 64 + n] - c_p[(kk * 5 + 4) * 64 + n];
      else        v = c_p[(kk * 5 + t) * 64 + n];
      Wt2[i] = (unsigned short)f2bfbits(v);
    }
  }
}

// ---------------- exclusive scan (thread-coarsened: 40 elems/thread) ----------------
__global__ void exscan_two(const int* __restrict__ cnt_f, const int* __restrict__ cnt_b,
                           int* __restrict__ rp_f, int* __restrict__ rp_b,
                           int* __restrict__ cur_f, int* __restrict__ cur_b, int n) {
  const int* cnt = (blockIdx.x == 0) ? cnt_f : cnt_b;
  int* rp  = (blockIdx.x == 0) ? rp_f  : rp_b;
  int* cur = (blockIdx.x == 0) ? cur_f : cur_b;
  __shared__ int sh[256];
  int t = threadIdx.x;
  int CH = (n + 255) / 256;
  int s0 = t * CH;
  int s1 = s0 + CH; if (s1 > n) s1 = n;
  int s = 0;
  for (int i = s0; i < s1; ++i) s += cnt[i];
  sh[t] = s;
  __syncthreads();
  for (int off = 1; off < 256; off <<= 1) {
    int x = (t >= off) ? sh[t - off] : 0;
    __syncthreads();
    sh[t] += x;
    __syncthreads();
  }
  int run = sh[t] - s;                 // exclusive prefix for this thread's chunk
  for (int i = s0; i < s1; ++i) {
    rp[i] = run; cur[i] = run; run += cnt[i];
  }
  if (t == 255) rp[n] = sh[255];
}

// ---------------- CSR fill: packed (col, w) uint2 ----------------
__global__ void fill_csr(const int* __restrict__ idx, const float* __restrict__ w,
                         const float* __restrict__ deg_f, const float* __restrict__ deg_b,
                         int* __restrict__ cur_f, int* __restrict__ cur_b,
                         uint2* __restrict__ cwf, uint2* __restrict__ cwb,
                         const int* __restrict__ flag) {
  int e = blockIdx.x * 256 + threadIdx.x;
  int is64 = flag[0];
  if (e < En) {
    int s = gidx(idx, e, is64);
    int d = gidx(idx, En + e, is64);
    float we = w[e];
    int pf = atomicAdd(&cur_f[d], 1);
    cwf[pf] = make_uint2((unsigned int)s, __float_as_uint(we / deg_f[s]));
    int pb = atomicAdd(&cur_b[s], 1);
    cwb[pb] = make_uint2((unsigned int)d, __float_as_uint(we / deg_b[d]));
  }
}

// ---------------- XCD-sliced propagation, multi-edge waves, scalar descriptors ----
// Node rows of RU4 uint4 are split into 8 channel slices of ACT uint4.
// slice = blockIdx & 7 -> each XCD gathers only its own 3.84/2.56 MB slice,
// L2-resident (verified FETCH 627->175 MB in R1).
// One row per wave; EPW edges per gather instruction (R7: -25% total).
// Edge descriptors at WAVE-UNIFORM indices (-> s_load scalar pipe; R3/R4/R5:
// per-lane/nontemporal descriptor loads force the vector path, up to -2x),
// then per-lane cndmask-selected by group id.
// R8: 32-bit umul24 addressing + packed f32 accumulation (-4%).
// R9/R10 diagnosis: L1/L2 line-rate bound (R8 -25% VALU -> -4% time);
// structure FROZEN at this formulation's floor.
template<int RU4, int ACT, int EPW>
__device__ __forceinline__ void prop_rowX(const uint4v* __restrict__ in,
                                          uint4v* __restrict__ out,
                                          const int* __restrict__ rp,
                                          const uint2* __restrict__ cw,
                                          int row, int slice, int lane, float alpha) {
  constexpr int GSZ = 64 / EPW;
  constexpr unsigned RB = (unsigned)RU4 * 16u;   // row bytes (3072 / 2048)
  int grp = (EPW == 2) ? (lane >> 5) : (lane >> 4);
  int lg = lane & (GSZ - 1);
  int lgc = (lg < ACT) ? lg : 0;       // pad lanes duplicate lane 0's line (coalesced, free)
  unsigned laneByte = (unsigned)(slice * ACT + lgc) * 16u;
  const char* __restrict__ inB = (const char*)in;
  int jb = __builtin_amdgcn_readfirstlane(rp[row]);
  int je = __builtin_amdgcn_readfirstlane(rp[row + 1]);
  int len = je - jb;

  f32x2 a0 = {0.f, 0.f}, a1 = {0.f, 0.f}, a2 = {0.f, 0.f}, a3 = {0.f, 0.f};

  constexpr int STEP = 4 * EPW;        // 4 gather instrs in flight per wave
  int i = jb;
  int eM = jb + (len / STEP) * STEP;
  for (; i < eM; i += STEP) {
    #pragma unroll
    for (int k = 0; k < 4; ++k) {
      unsigned int col; float w;
      {
        uint2 e0 = cw[i + k * EPW + 0];
        uint2 e1 = cw[i + k * EPW + 1];
        col = (grp & 1) ? e1.x : e0.x;
        w = __uint_as_float((grp & 1) ? e1.y : e0.y);
        if (EPW == 4) {
          uint2 e2 = cw[i + k * EPW + 2];
          uint2 e3 = cw[i + k * EPW + 3];
          unsigned int colB = (grp & 1) ? e3.x : e2.x;
          float wB = __uint_as_float((grp & 1) ? e3.y : e2.y);
          col = (grp & 2) ? colB : col;
          w = (grp & 2) ? wB : w;
        }
      }
      unsigned off = __umul24(col, RB) + laneByte;     // u32, < 31 MB: safe
      uint4v q = *(const uint4v*)(inB + off);
      f32x2 wv = {w, w};
      f32x2 v0 = {bflo(q.x), bfhi(q.x)};
      f32x2 v1 = {bflo(q.y), bfhi(q.y)};
      f32x2 v2 = {bflo(q.z), bfhi(q.z)};
      f32x2 v3 = {bflo(q.w), bfhi(q.w)};
      a0 += wv * v0; a1 += wv * v1; a2 += wv * v2; a3 += wv * v3;
    }
  }
  // masked tail, EPW edges per step (clamped uniform descriptor indices)
  for (; i < je; i += EPW) {
    unsigned int col; float w;
    {
      uint2 e0 = cw[i + 0];
      uint2 e1 = cw[(i + 1 < je) ? i + 1 : i];
      col = (grp & 1) ? e1.x : e0.x;
      w = __uint_as_float((grp & 1) ? e1.y : e0.y);
      if (EPW == 4) {
        uint2 e2 = cw[(i + 2 < je) ? i + 2 : i];
        uint2 e3 = cw[(i + 3 < je) ? i + 3 : i];
        unsigned int colB = (grp & 1) ? e3.x : e2.x;
        float wB = __uint_as_float((grp & 1) ? e3.y : e2.y);
        col = (grp & 2) ? colB : col;
        w = (grp & 2) ? wB : w;
      }
    }
    if (i + grp >= je) w = 0.f;        // invalid lanes contribute 0 (clamped addr is safe)
    unsigned off = __umul24(col, RB) + laneByte;
    uint4v q = *(const uint4v*)(inB + off);
    f32x2 wv = {w, w};
    f32x2 v0 = {bflo(q.x), bfhi(q.x)};
    f32x2 v1 = {bflo(q.y), bfhi(q.y)};
    f32x2 v2 = {bflo(q.z), bfhi(q.z)};
    f32x2 v3 = {bflo(q.w), bfhi(q.w)};
    a0 += wv * v0; a1 += wv * v1; a2 += wv * v2; a3 += wv * v3;
  }

  // cross-group reduce
  if (EPW == 4) {
    a0.x += __shfl_xor(a0.x, 16); a0.y += __shfl_xor(a0.y, 16);
    a1.x += __shfl_xor(a1.x, 16); a1.y += __shfl_xor(a1.y, 16);
    a2.x += __shfl_xor(a2.x, 16); a2.y += __shfl_xor(a2.y, 16);
    a3.x += __shfl_xor(a3.x, 16); a3.y += __shfl_xor(a3.y, 16);
  }
  a0.x += __shfl_xor(a0.x, 32); a0.y += __shfl_xor(a0.y, 32);
  a1.x += __shfl_xor(a1.x, 32); a1.y += __shfl_xor(a1.y, 32);
  a2.x += __shfl_xor(a2.x, 32); a2.y += __shfl_xor(a2.y, 32);
  a3.x += __shfl_xor(a3.x, 32); a3.y += __shfl_xor(a3.y, 32);

  if (grp == 0 && lg < ACT) {
    uint4v o;
    o.x = pack2(alpha * a0.x, alpha * a0.y);
    o.y = pack2(alpha * a1.x, alpha * a1.y);
    o.z = pack2(alpha * a2.x, alpha * a2.y);
    o.w = pack2(alpha * a3.x, alpha * a3.y);
    out[(size_t)row * RU4 + slice * ACT + lg] = o;
  }
}

template<int RU4, int ACT, int EPW>
__launch_bounds__(256)
__global__ void prop_dualX(const uint4v* __restrict__ in,
                           uint4v* __restrict__ outF, uint4v* __restrict__ outB,
                           const int* __restrict__ rp_f, const uint2* __restrict__ cwf,
                           const int* __restrict__ rp_b, const uint2* __restrict__ cwb) {
  int lane = threadIdx.x & 63;
  int wave = threadIdx.x >> 6;
  int slice = blockIdx.x & 7;
  int row = ((blockIdx.x >> 3) << 2) + wave;
  prop_rowX<RU4, ACT, EPW>(in, outF, rp_f, cwf, row, slice, lane, 1.f);
  prop_rowX<RU4, ACT, EPW>(in, outB, rp_b, cwb, row, slice, lane, 1.f);
}

template<int RU4, int ACT, int EPW>
__launch_bounds__(256)
__global__ void prop_ckX(const uint4v* __restrict__ in, uint4v* __restrict__ out,
                         const int* __restrict__ rp, const uint2* __restrict__ cw,
                         float alpha) {
  int lane = threadIdx.x & 63;
  int wave = threadIdx.x >> 6;
  int slice = blockIdx.x & 7;
  int row = ((blockIdx.x >> 3) << 2) + wave;
  prop_rowX<RU4, ACT, EPW>(in, out, rp, cw, row, slice, lane, alpha);
}

// ---------------- MFMA multi-term GEMM ----------------
// C[128 x NT] per block; 4 waves, each 32 x NT. K = nterms*96.
// Weight columns for loop term t are taken at (t0 + t)*96.
// LDS tiles are LINEAR (row stride 96 shorts = 192 B): ds_read_b128 by a wave64
// covers every bank exactly 8x (the hardware floor), so the old +8 padding was
// not load-bearing. Linear layout enables global_load_lds (direct HBM->LDS,
// no VGPR round-trip) for all contiguous A-terms and all B-tiles; the
// rh-split A-terms keep VGPR staging (note ci0 == slot*8 -> also linear).
// MFMA layouts (verified): A[m=lane&15][k=quad*8+j]; B[k=quad*8+j][n=lane&15];
//                          C/D col=lane&15, row=quad*4+reg.
// MODE 0: conv1 epilogue: v=sigmoid(bias+acc); col<64 -> rh0=v*h (bf16); else U=v (bf16)
// MODE 1: outp = bias + acc (f32, batch-major)
// MODE 2: cp = outp + acc; c=tanh(tanh(cp)); u from U_in; outp = u*h + (1-u)*c
struct Msrc {
  const uint4* xs[5];
  const uint4* rh[5];
};

template<int NT, int MODE>
__device__ __forceinline__ void gemm_body(int blk, Msrc g, int nterms, int t0,
                          const unsigned short* __restrict__ Wt,
                          const float* __restrict__ bias,
                          float* __restrict__ outp,
                          unsigned short* __restrict__ rh0_s,
                          unsigned short* __restrict__ U_out,
                          const unsigned short* __restrict__ U_in,
                          const float* __restrict__ hglob) {
  constexpr int NJ = NT / 16;
  __shared__ __align__(16) unsigned short As[128 * 96];
  __shared__ __align__(16) unsigned short Bs[NT * 96];

  int m0 = blk * 128;
  int tid = threadIdx.x;
  int wave = tid >> 6;
  int lane = tid & 63;
  int quad = lane >> 4;
  int lm = lane & 15;
  int wm = wave * 32;
  int nodeBase = m0 >> 4;

  f32x4 acc[2][NJ];
  #pragma unroll
  for (int i = 0; i < 2; ++i)
    #pragma unroll
    for (int j = 0; j < NJ; ++j) acc[i][j] = (f32x4){0.f, 0.f, 0.f, 0.f};

  for (int t = 0; t < nterms; ++t) {
    const uint4* xs4 = g.xs[t];
    const uint4* rh4 = g.rh[t];
    if (rh4 == nullptr) {
      const uint4* src = xs4 + (size_t)m0 * 12;
#if HAVE_GLL
      #pragma unroll
      for (int it = 0; it < 6; ++it) {
        int q = tid + it * 256;
        gll16(src + q, (char*)As + (q & ~63) * 16);
      }
#else
      #pragma unroll
      for (int it = 0; it < 6; ++it) {
        int q = tid + it * 256;
        uint4 v = src[q];
        *(uint4*)&As[q * 8] = v;
      }
#endif
    } else {
      #pragma unroll
      for (int it = 0; it < 6; ++it) {
        int q = tid + it * 256;
        int row = q / 12, slot = q % 12;
        int node = nodeBase + (row >> 4);
        int b = row & 15;
        uint4 v;
        if (slot < 4) v = xs4[(size_t)node * 192 + b * 12 + slot];
        else          v = rh4[(size_t)node * 128 + b * 8 + (slot - 4)];
        *(uint4*)&As[q * 8] = v;       // ci0 == slot*8 -> linear position q*16B
      }
    }
#if HAVE_GLL
    #pragma unroll
    for (int it = 0; it < NT * 12 / 256; ++it) {
      int q = tid + it * 256;
      int n = q / 12, slot = q % 12;
      gll16(Wt + (size_t)n * 480 + (t0 + t) * 96 + slot * 8, (char*)Bs + (q & ~63) * 16);
    }
#else
    for (int q = tid; q < NT * 12; q += 256) {
      int n = q / 12, slot = q % 12;
      uint4 v = *(const uint4*)(Wt + (size_t)n * 480 + (t0 + t) * 96 + slot * 8);
      *(uint4*)&Bs[q * 8] = v;
    }
#endif
    __syncthreads();

    #pragma unroll
    for (int k32 = 0; k32 < 3; ++k32) {
      int kb = k32 * 32 + quad * 8;
      short8 a0 = *(const short8*)&As[(wm + lm) * 96 + kb];
      short8 a1 = *(const short8*)&As[(wm + 16 + lm) * 96 + kb];
      #pragma unroll
      for (int j = 0; j < NJ; ++j) {
        short8 bf = *(const short8*)&Bs[(j * 16 + lm) * 96 + kb];
        acc[0][j] = __builtin_amdgcn_mfma_f32_16x16x32_bf16(a0, bf, acc[0][j], 0, 0, 0);
        acc[1][j] = __builtin_amdgcn_mfma_f32_16x16x32_bf16(a1, bf, acc[1][j], 0, 0, 0);
      }
    }
    __syncthreads();
  }

  #pragma unroll
  for (int i = 0; i < 2; ++i) {
    #pragma unroll
    for (int j = 0; j < NJ; ++j) {
      int col = j * 16 + lm;
      #pragma unroll
      for (int r = 0; r < 4; ++r) {
        int row = m0 + wm + i * 16 + quad * 4 + r;
        int node = row >> 4, b = row & 15;
        float v = acc[i][j][r];
        if (MODE == 0) {
          float s = 1.f / (1.f + expf(-(bias[col] + v)));
          if (col < COUTn) {
            float hv = hglob[((size_t)b * Nn + node) * COUTn + col];
            rh0_s[(size_t)row * 64 + col] = (unsigned short)f2bfbits(s * hv);
          } else {
            U_out[(size_t)row * 64 + (col - COUTn)] = (unsigned short)f2bfbits(s);
          }
        } else if (MODE == 1) {
          outp[((size_t)b * Nn + node) * COUTn + col] = bias[col] + v;
        } else {
          size_t oa = ((size_t)b * Nn + node) * COUTn + col;
          float cp = outp[oa] + v;
          float c = tanhf(tanhf(cp));
          float u = bf2f(U_in[(size_t)row * 64 + col]);
          outp[oa] = u * hglob[oa] + (1.f - u) * c;
        }
      }
    }
  }
}

template<int NT, int MODE>
__launch_bounds__(256)
__global__ void gemm_mfma(Msrc g, int nterms, int t0,
                          const unsigned short* __restrict__ Wt,
                          const float* __restrict__ bias,
                          float* __restrict__ outp,
                          unsigned short* __restrict__ rh0_s,
                          unsigned short* __restrict__ U_out,
                          const unsigned short* __restrict__ U_in,
                          const float* __restrict__ hglob) {
  gemm_body<NT, MODE>(blockIdx.x, g, nterms, t0, Wt, bias, outp, rh0_s, U_out, U_in, hglob);
}

// ---------------- fused: gemm2a (MODE 1) overlapped with conv2 ck F/B ----------------
// Regions: [0,1256) gemm (1250 active; gemm blocks start first = long-running),
// [1256, 21256) ck-F, [21256, 41256) ck-B. All bases %8==0 so slice=b2&7 stays
// XCD-consistent. Hazard-free: cks write NEW rh2 buffers (not rh0/rh1f that the
// gemm reads concurrently).
__launch_bounds__(256)
__global__ void fused_g2a(Msrc g,
                          const unsigned short* __restrict__ Wt,
                          const float* __restrict__ bias,
                          float* __restrict__ outp,
                          const uint4v* __restrict__ inF, uint4v* __restrict__ outF,
                          const int* __restrict__ rp_f, const uint2* __restrict__ cwf,
                          const uint4v* __restrict__ inB, uint4v* __restrict__ outB,
                          const int* __restrict__ rp_b, const uint2* __restrict__ cwb) {
  int b = blockIdx.x;
  if (b < 1256) {
    if (b < 1250)
      gemm_body<64, 1>(b, g, 3, 0, Wt, bias, outp, nullptr, nullptr, nullptr, nullptr);
    return;
  }
  int lane = threadIdx.x & 63;
  int wave = threadIdx.x >> 6;
  if (b < 21256) {
    int b2 = b - 1256;
    prop_rowX<128, 16, 4>(inF, outF, rp_f, cwf, ((b2 >> 3) << 2) + wave, b2 & 7, lane, 2.f);
  } else {
    int b2 = b - 21256;
    prop_rowX<128, 16, 4>(inB, outB, rp_b, cwb, ((b2 >> 3) << 2) + wave, b2 & 7, lane, 2.f);
  }
}

// ---------------- host ----------------
extern "C" void kernel_launch(void* const* d_in, const int* in_sizes, int n_in,
                              void* d_out, int out_size, void* d_ws, size_t ws_size,
                              hipStream_t stream) {
  const float* x   = (const float*)d_in[0];
  const float* h   = (const float*)d_in[1];
  const int*   idx = (const int*)d_in[2];
  const float* ew  = (const float*)d_in[3];
  const float* ru_param = (const float*)d_in[4];
  const float* ru_bias  = (const float*)d_in[5];
  const float* c_param  = (const float*)d_in[6];
  const float* c_bias   = (const float*)d_in[7];
  float* outp = (float*)d_out;
  (void)in_sizes; (void)n_in; (void)out_size;

  char* ws = (char*)d_ws;
  size_t off = 0;
  auto alloc = [&](size_t bytes) -> char* {
    char* p = ws + off;
    off += (bytes + 255) & ~(size_t)255;
    return p;
  };

  float* deg_f = (float*)alloc(40960);
  float* deg_b = (float*)alloc(40960);
  int*   cnt_f = (int*)alloc(40960);
  int*   cnt_b = (int*)alloc(40960);
  int*   rp_f  = (int*)alloc((Nn + 1) * sizeof(int));
  int*   rp_b  = (int*)alloc((Nn + 1) * sizeof(int));
  int*   cur_f = (int*)alloc(Nn * sizeof(int));
  int*   cur_b = (int*)alloc(Nn * sizeof(int));
  int*   flag  = (int*)alloc(256);
  uint2* cwf   = (uint2*)alloc((size_t)En * 8);
  uint2* cwb   = (uint2*)alloc((size_t)En * 8);
  unsigned short* Wt1 = (unsigned short*)alloc(128 * 480 * 2);
  unsigned short* Wt2 = (unsigned short*)alloc(64 * 480 * 2);

  unsigned int* A0   = (unsigned int*)alloc((size_t)Nn * WROWU * 4);
  unsigned int* T1f  = (unsigned int*)alloc((size_t)Nn * WROWU * 4);
  unsigned int* T1b  = (unsigned int*)alloc((size_t)Nn * WROWU * 4);
  unsigned int* T2f  = (unsigned int*)alloc((size_t)Nn * WROWU * 4);
  unsigned int* T2b  = (unsigned int*)alloc((size_t)Nn * WROWU * 4);
  unsigned int* rh0  = (unsigned int*)alloc((size_t)Nn * RHU * 4);
  unsigned int* rh1f = (unsigned int*)alloc((size_t)Nn * RHU * 4);
  unsigned int* rh1b = (unsigned int*)alloc((size_t)Nn * RHU * 4);
  unsigned int* Ubuf = (unsigned int*)alloc((size_t)Nn * RHU * 4);
  // extra buffers for the fused (overlapped) conv2 second-order pass
  unsigned int* rh2fN = (unsigned int*)alloc((size_t)Nn * RHU * 4);
  unsigned int* rh2bN = (unsigned int*)alloc((size_t)Nn * RHU * 4);
  bool bigws = (off <= ws_size);       // fall back to sequential if ws too small

  hipMemsetAsync(ws, 0, 4 * 40960, stream);
  detect_idx<<<1, 64, 0, stream>>>(idx, flag);
  deg_x0_wt<<<GDEG + GX0 + 240, 256, 0, stream>>>(
      idx, ew, deg_f, deg_b, cnt_f, cnt_b, flag,
      x, h, A0, ru_param, c_param, Wt1, Wt2);
  exscan_two<<<2, 256, 0, stream>>>(cnt_f, cnt_b, rp_f, rp_b, cur_f, cur_b, Nn);
  fill_csr<<<En / 256, 256, 0, stream>>>(idx, ew, deg_f, deg_b, cur_f, cur_b,
                                         cwf, cwb, flag);

  const int gP = (Nn / 4) * 8;   // 4 rows/block (1 per wave) x 8 XCD slices

  // ===== conv1 diffusion (rows of 192 uint4, slices of 24 uint4, 2 edges/gather) =====
  prop_dualX<192, 24, 2><<<gP, 256, 0, stream>>>(
      (const uint4v*)A0, (uint4v*)T1f, (uint4v*)T1b, rp_f, cwf, rp_b, cwb);
  prop_ckX<192, 24, 2><<<gP, 256, 0, stream>>>(
      (const uint4v*)T1f, (uint4v*)T2f, rp_f, cwf, 2.f);
  prop_ckX<192, 24, 2><<<gP, 256, 0, stream>>>(
      (const uint4v*)T1b, (uint4v*)T2b, rp_b, cwb, 2.f);

  // ===== conv1 projection: one MFMA GEMM K=480, fused sigmoid + r*h + u-store =====
  Msrc g1;
  g1.xs[0] = (const uint4*)A0;  g1.rh[0] = nullptr;
  g1.xs[1] = (const uint4*)T1f; g1.rh[1] = nullptr;
  g1.xs[2] = (const uint4*)T1b; g1.rh[2] = nullptr;
  g1.xs[3] = (const uint4*)T2f; g1.rh[3] = nullptr;
  g1.xs[4] = (const uint4*)T2b; g1.rh[4] = nullptr;
  gemm_mfma<128, 0><<<MROWS / 128, 256, 0, stream>>>(
      g1, 5, 0, Wt1, ru_bias, nullptr,
      (unsigned short*)rh0, (unsigned short*)Ubuf, nullptr, h);

  // ===== conv2 diffusion on rh (rows of 128 uint4, slices of 16 uint4, 4 edges/gather) =====
  prop_dualX<128, 16, 4><<<gP, 256, 0, stream>>>(
      (const uint4v*)rh0, (uint4v*)rh1f, (uint4v*)rh1b, rp_f, cwf, rp_b, cwb);

  // conv2 pass A (terms 0,1,2) overlapped with the rh second-order propagations
  Msrc g2a;
  g2a.xs[0] = (const uint4*)A0;  g2a.rh[0] = (const uint4*)rh0;
  g2a.xs[1] = (const uint4*)T1f; g2a.rh[1] = (const uint4*)rh1f;
  g2a.xs[2] = (const uint4*)T1b; g2a.rh[2] = (const uint4*)rh1b;
  g2a.xs[3] = nullptr; g2a.rh[3] = nullptr;
  g2a.xs[4] = nullptr; g2a.rh[4] = nullptr;

  const uint4* g2b_rh0;
  const uint4* g2b_rh1;
  if (bigws) {
    fused_g2a<<<41256, 256, 0, stream>>>(
        g2a, Wt2, c_bias, outp,
        (const uint4v*)rh1f, (uint4v*)rh2fN, rp_f, cwf,
        (const uint4v*)rh1b, (uint4v*)rh2bN, rp_b, cwb);
    g2b_rh0 = (const uint4*)rh2fN;
    g2b_rh1 = (const uint4*)rh2bN;
  } else {
    gemm_mfma<64, 1><<<MROWS / 128, 256, 0, stream>>>(
        g2a, 3, 0, Wt2, c_bias, outp, nullptr, nullptr, nullptr, nullptr);
    prop_ckX<128, 16, 4><<<gP, 256, 0, stream>>>(
        (const uint4v*)rh1f, (uint4v*)rh0, rp_f, cwf, 2.f);   // rh2f -> rh0
    prop_ckX<128, 16, 4><<<gP, 256, 0, stream>>>(
        (const uint4v*)rh1b, (uint4v*)rh1f, rp_b, cwb, 2.f);  // rh2b -> rh1f
    g2b_rh0 = (const uint4*)rh0;
    g2b_rh1 = (const uint4*)rh1f;
  }

  // conv2 pass B: terms 3,4 (weight base t0=3) + fused GRU final
  Msrc g2b;
  g2b.xs[0] = (const uint4*)T2f; g2b.rh[0] = g2b_rh0;
  g2b.xs[1] = (const uint4*)T2b; g2b.rh[1] = g2b_rh1;
  g2b.xs[2] = nullptr; g2b.rh[2] = nullptr;
  g2b.xs[3] = nullptr; g2b.rh[3] = nullptr;
  g2b.xs[4] = nullptr; g2b.rh[4] = nullptr;
  gemm_mfma<64, 2><<<MROWS / 128, 256, 0, stream>>>(
      g2b, 2, 3, Wt2, c_bias, outp, nullptr, nullptr,
      (const unsigned short*)Ubuf, h);
}